// Round 4
// baseline (9632.739 us; speedup 1.0000x reference)
//
#include <hip/hip_runtime.h>
#include <hip/hip_bf16.h>

// ResNetTTT fp32. Round 4: ttt_kernel at 512 threads / __launch_bounds__(512,2)
// (2 waves/SIMD, 256-VGPR cap), W1 cols in registers, W2 ONLY in swizzled LDS
// (fused RMW update by waves 0-3), per-thread work halved vs round 3.

#define ERF_CF 0.70710678118654752f
#define PDF_CF 0.3989422804014327f
#define ETA 0.025f   // TTT_LR / MB = 0.1/4

__device__ __forceinline__ float wsum(float v) {
#pragma unroll
  for (int o = 32; o > 0; o >>= 1) v += __shfl_xor(v, o, 64);
  return v;
}

// ---------------------------------------------------------------------------
// prep: transpose conv weights into GEMM-friendly [k][co] layout
// ---------------------------------------------------------------------------
__global__ void prep_w(const float* __restrict__ c1w, const float* __restrict__ cw,
                       float* __restrict__ wt1, float* __restrict__ wt) {
  int id = blockIdx.x * 256 + threadIdx.x;
  if (id < 16384) {
    int ci = id >> 8, co = id & 255;
    wt1[id] = c1w[co * 64 + ci];
  }
  int id2 = id - 16384;
  if (id2 >= 0 && id2 < 1572864) {
    int cv = id2 / 196608;
    int r = id2 - cv * 196608;
    int k = r >> 8, co = r & 255;
    int tt = k >> 8, ci = k & 255;
    wt[id2] = cw[((cv * 256 + co) * 256 + ci) * 3 + tt];
  }
}

__global__ void zero_halo(float* __restrict__ bufA, float* __restrict__ bufB) {
  int id = blockIdx.x * 256 + threadIdx.x;  // 0..4095
  int c = id & 255;
  int row = (id >> 8) & 1;
  int b = (id >> 9) & 3;
  float* p = (id >> 11) ? bufB : bufA;
  p[(b * 1026 + row * 1025) * 256 + c] = 0.0f;
}

// ---------------------------------------------------------------------------
// Generic tiled fp32 GEMM (unchanged)
// ---------------------------------------------------------------------------
template <int BIAS, int RELU, int RES, int OST, int ACC>
__global__ __launch_bounds__(256) void gemm_k(
    const float* __restrict__ A, const float* __restrict__ Wt,
    const float* __restrict__ bias, const float* __restrict__ res,
    float* __restrict__ out, float* __restrict__ accp,
    int M, int N, int K, int lda, int haloA) {
  __shared__ float As[16][68];
  __shared__ float Bs[16][64];
  const int tid = threadIdx.x;
  const int bm = blockIdx.x * 64, bn = blockIdx.y * 64;
  const int tx = tid & 15, ty = tid >> 4;
  float acc[4][4] = {};

  for (int k0 = 0; k0 < K; k0 += 16) {
#pragma unroll
    for (int i = 0; i < 4; ++i) {
      int idx = tid + i * 256;
      int kk = idx & 15, mm = idx >> 4;
      int m = bm + mm;
      int rb = m * lda + (haloA ? ((m >> 10) << 9) : 0);
      As[kk][mm] = A[rb + k0 + kk];
    }
#pragma unroll
    for (int i = 0; i < 4; ++i) {
      int idx = tid + i * 256;
      int nn = idx & 63, kk = idx >> 6;
      Bs[kk][nn] = Wt[(k0 + kk) * N + bn + nn];
    }
    __syncthreads();
#pragma unroll
    for (int kk = 0; kk < 16; ++kk) {
      float4 av = *(const float4*)&As[kk][ty * 4];
      float4 bv = *(const float4*)&Bs[kk][tx * 4];
      float aa[4] = {av.x, av.y, av.z, av.w};
      float bb[4] = {bv.x, bv.y, bv.z, bv.w};
#pragma unroll
      for (int i = 0; i < 4; ++i)
#pragma unroll
        for (int j = 0; j < 4; ++j) acc[i][j] = fmaf(aa[i], bb[j], acc[i][j]);
    }
    __syncthreads();
  }

  const int n0 = bn + tx * 4;
#pragma unroll
  for (int i = 0; i < 4; ++i) {
    int m = bm + ty * 4 + i;
    int b_ = m >> 10, l = m & 1023;
    float v[4];
#pragma unroll
    for (int j = 0; j < 4; ++j) {
      float x = acc[i][j];
      if constexpr (BIAS) x += bias[n0 + j];
      if constexpr (RELU) x = fmaxf(x, 0.0f);
      if constexpr (RES) x += res[m * N + n0 + j];
      v[j] = x;
    }
    float4 vv = make_float4(v[0], v[1], v[2], v[3]);
    if constexpr (OST == 0) {
      *(float4*)&out[m * N + n0] = vv;
    } else if constexpr (OST == 1) {
      *(float4*)&out[(b_ * 1026 + l + 1) * 256 + n0] = vv;
    } else {
      int hq = n0 >> 6;
      int oidx = (((b_ * 4 + hq) * 1024 + l) << 6) + (n0 & 63);
      *(float4*)&out[oidx] = vv;
    }
    if constexpr (ACC == 1) {
      *(float4*)&accp[m * 256 + n0] = vv;
    } else if constexpr (ACC == 2) {
      float4 s = *(const float4*)&accp[m * 256 + n0];
      s.x += vv.x; s.y += vv.y; s.z += vv.z; s.w += vv.w;
      *(float4*)&accp[m * 256 + n0] = s;
    }
  }
}

// ---------------------------------------------------------------------------
// LayerNorm over last dim (256). 256 threads = 4 rows per block.
// ---------------------------------------------------------------------------
__global__ __launch_bounds__(256) void ln_kernel(const float* __restrict__ in,
                                                 float* __restrict__ o,
                                                 const float* __restrict__ w,
                                                 const float* __restrict__ bb,
                                                 float eps) {
  int row = blockIdx.x * 4 + (threadIdx.x >> 6);
  int l = threadIdx.x & 63;
  float4 v = ((const float4*)(in + (long)row * 256))[l];
  float s = wsum(v.x + v.y + v.z + v.w);
  float mu = s * (1.0f / 256.0f);
  float dx = v.x - mu, dy = v.y - mu, dz = v.z - mu, dw = v.w - mu;
  float ss = wsum(dx * dx + dy * dy + dz * dz + dw * dw);
  float rstd = rsqrtf(ss * (1.0f / 256.0f) + eps);
  float4 wv = ((const float4*)w)[l];
  float4 bv = ((const float4*)bb)[l];
  float4 r;
  r.x = wv.x * dx * rstd + bv.x;
  r.y = wv.y * dy * rstd + bv.y;
  r.z = wv.z * dz * rstd + bv.z;
  r.w = wv.w * dw * rstd + bv.w;
  ((float4*)(o + (long)row * 256))[l] = r;
}

// ---------------------------------------------------------------------------
// TTT scan: one block of 512 threads (8 waves, 2/SIMD) per (b,h) chain.
// t: c = t&255 (column), g = t>>8 (rows {2g,2g+1}); w8 = t>>6, lane = t&63.
// Registers: w1[64] = W1[:,c] (duplicated across g; bit-identical updates).
// LDS: W2L[k][(j+k)&63] rotation swizzle; stages B/G read columns, stage D
// reads row c and (waves 0-3 only) RMW-updates it.
// ---------------------------------------------------------------------------
__global__ __launch_bounds__(512, 2) void ttt_kernel(
    const float* __restrict__ XQ, const float* __restrict__ XK,
    const float* __restrict__ XV, const float* __restrict__ W1i,
    const float* __restrict__ B1i, const float* __restrict__ W2i,
    const float* __restrict__ B2i, const float* __restrict__ LNW,
    const float* __restrict__ LNB, float* __restrict__ outp) {
  const int bh = blockIdx.x;
  const int b = bh >> 2, h = bh & 3;
  const int t = threadIdx.x;      // 0..511
  const int w8 = t >> 6;          // 0..7
  const int lane = t & 63;
  const int c = t & 255;          // column 0..255
  const int g = t >> 8;           // 0/1
  const int m0 = 2 * g, m1 = 2 * g + 1;
  const int kb = w8 * 32;         // k-slice base for B/G partials

  __shared__ float xkL[256], xvL[256], xqL[256];
  __shared__ float X2s[4][256];
  __shared__ float gZ2s[4][64];
  __shared__ float gZ1s[4][256];
  __shared__ float redS[8][4][64];
  __shared__ float b2s[64], lwS[64], lbS[64];
  __shared__ float W2L[256][64];

  float w1[64];
#pragma unroll
  for (int k = 0; k < 64; ++k) w1[k] = W1i[(h * 64 + k) * 256 + c];
  float b1r = B1i[h * 256 + c];
  // W2 -> LDS, rotation swizzle (512 threads, 32 elems each)
#pragma unroll
  for (int i = 0; i < 32; ++i) {
    int id = t + i * 512;
    int k = id >> 6, j = id & 63;
    W2L[k][(j + k) & 63] = W2i[(h * 256 + k) * 64 + j];
  }
  if (t < 64) {
    b2s[t] = B2i[h * 64 + t];
    lwS[t] = LNW[h * 64 + t];
    lbS[t] = LNB[h * 64 + t];
  }

  const long chain = (long)bh * (1024 * 64);
  float rk = 0.0f, rv = 0.0f, rq = 0.0f;
  if (t < 256) { rk = XK[chain + t]; rv = XV[chain + t]; }
  else         { rq = XQ[chain + (t - 256)]; }
  __syncthreads();

  for (int n = 0; n < 256; ++n) {
    if (t < 256) { xkL[t] = rk; xvL[t] = rv; } else { xqL[t - 256] = rq; }
    __syncthreads();  // B1

    // ---- A: Z1 rows m0,m1 col c ; X2 = gelu ----
    float am0 = b1r, am1 = b1r;
    {
      const float* xk0 = &xkL[m0 * 64];
      const float* xk1 = &xkL[m1 * 64];
#pragma unroll
      for (int k4 = 0; k4 < 64; k4 += 4) {
        float4 a0 = *(const float4*)&xk0[k4];
        float4 a1 = *(const float4*)&xk1[k4];
        float w0 = w1[k4], wA = w1[k4 + 1], wB = w1[k4 + 2], wC = w1[k4 + 3];
        am0 = fmaf(a0.x, w0, am0); am0 = fmaf(a0.y, wA, am0);
        am0 = fmaf(a0.z, wB, am0); am0 = fmaf(a0.w, wC, am0);
        am1 = fmaf(a1.x, w0, am1); am1 = fmaf(a1.y, wA, am1);
        am1 = fmaf(a1.z, wB, am1); am1 = fmaf(a1.w, wC, am1);
      }
    }
    const float z10 = am0, z11 = am1;
    const float er0 = erff(z10 * ERF_CF), er1 = erff(z11 * ERF_CF);
    X2s[m0][c] = 0.5f * z10 * (1.0f + er0);
    X2s[m1][c] = 0.5f * z11 * (1.0f + er1);
    __syncthreads();  // B2

    // ---- B: Z2 partials over k-slice [kb,kb+32), column j=lane ----
    {
      float pp0 = 0, pp1 = 0, pp2 = 0, pp3 = 0;
#pragma unroll
      for (int k4 = 0; k4 < 32; k4 += 4) {
        int kk = kb + k4;
        float4 y0 = *(const float4*)&X2s[0][kk];
        float4 y1 = *(const float4*)&X2s[1][kk];
        float4 y2 = *(const float4*)&X2s[2][kk];
        float4 y3 = *(const float4*)&X2s[3][kk];
        float wv0 = W2L[kk][(lane + kk) & 63];
        float wv1 = W2L[kk + 1][(lane + kk + 1) & 63];
        float wv2 = W2L[kk + 2][(lane + kk + 2) & 63];
        float wv3 = W2L[kk + 3][(lane + kk + 3) & 63];
        pp0 = fmaf(y0.x, wv0, pp0); pp0 = fmaf(y0.y, wv1, pp0);
        pp0 = fmaf(y0.z, wv2, pp0); pp0 = fmaf(y0.w, wv3, pp0);
        pp1 = fmaf(y1.x, wv0, pp1); pp1 = fmaf(y1.y, wv1, pp1);
        pp1 = fmaf(y1.z, wv2, pp1); pp1 = fmaf(y1.w, wv3, pp1);
        pp2 = fmaf(y2.x, wv0, pp2); pp2 = fmaf(y2.y, wv1, pp2);
        pp2 = fmaf(y2.z, wv2, pp2); pp2 = fmaf(y2.w, wv3, pp2);
        pp3 = fmaf(y3.x, wv0, pp3); pp3 = fmaf(y3.y, wv1, pp3);
        pp3 = fmaf(y3.z, wv2, pp3); pp3 = fmaf(y3.w, wv3, pp3);
      }
      redS[w8][0][lane] = pp0;
      redS[w8][1][lane] = pp1;
      redS[w8][2][lane] = pp2;
      redS[w8][3][lane] = pp3;
    }
    __syncthreads();  // B3

    // ---- C: reduce + LN-l2-bwd -> gZ2s (waves 0-3: row m=w8, col lane) ----
    if (t < 256) {
      float z2 = b2s[lane];
#pragma unroll
      for (int q = 0; q < 8; ++q) z2 += redS[q][w8][lane];
      float mu = wsum(z2) * (1.0f / 64.0f);
      float dv = z2 - mu;
      float var = wsum(dv * dv) * (1.0f / 64.0f);
      float stdv = sqrtf(var + 1e-6f);
      float zhat = dv / stdv;
      float lwv = lwS[lane], lbv = lbS[lane];
      float tgt = xvL[w8 * 64 + lane] - xkL[w8 * 64 + lane];
      float gg = lwv * (lwv * zhat + lbv - tgt);
      float gs = wsum(gg) * (1.0f / 64.0f);
      float gzs = wsum(gg * zhat) * (1.0f / 64.0f);
      gZ2s[w8][lane] = (gg - gs - zhat * gzs) / stdv;
    }
    __syncthreads();  // B4

    // prefetch next step's inputs (hidden under D/E/F compute)
    if (n + 1 < 256) {
      const long nb = chain + (long)(n + 1) * 256;
      if (t < 256) { rk = XK[nb + t]; rv = XV[nb + t]; }
      else         { rq = XQ[nb + (t - 256)]; }
    }

    // ---- D: gZ1 rows m0,m1 (dot with W2 row c) + (g==0) W2L row RMW ----
    {
      const float xa0 = X2s[0][c], xa1 = X2s[1][c];
      const float xa2 = X2s[2][c], xa3 = X2s[3][c];
      const float* gA = &gZ2s[m0][0];
      const float* gB = &gZ2s[m1][0];
      float sD0 = 0, sD1 = 0;
#pragma unroll
      for (int p4 = 0; p4 < 64; p4 += 4) {
        float4 ga = *(const float4*)&gA[p4];
        float4 gb = *(const float4*)&gB[p4];
        float wv0 = W2L[c][(p4 + 0 + c) & 63];
        float wv1 = W2L[c][(p4 + 1 + c) & 63];
        float wv2 = W2L[c][(p4 + 2 + c) & 63];
        float wv3 = W2L[c][(p4 + 3 + c) & 63];
        sD0 = fmaf(ga.x, wv0, sD0); sD0 = fmaf(ga.y, wv1, sD0);
        sD0 = fmaf(ga.z, wv2, sD0); sD0 = fmaf(ga.w, wv3, sD0);
        sD1 = fmaf(gb.x, wv0, sD1); sD1 = fmaf(gb.y, wv1, sD1);
        sD1 = fmaf(gb.z, wv2, sD1); sD1 = fmaf(gb.w, wv3, sD1);
        if (g == 0) {
          float4 q0 = *(const float4*)&gZ2s[0][p4];
          float4 q1 = *(const float4*)&gZ2s[1][p4];
          float4 q2 = *(const float4*)&gZ2s[2][p4];
          float4 q3 = *(const float4*)&gZ2s[3][p4];
#define W2RMW(J, C, WV)                                       \
  {                                                           \
    float u = xa0 * q0.C;                                     \
    u = fmaf(xa1, q1.C, u);                                   \
    u = fmaf(xa2, q2.C, u);                                   \
    u = fmaf(xa3, q3.C, u);                                   \
    W2L[c][(p4 + J + c) & 63] = fmaf(-ETA, u, WV);            \
  }
          W2RMW(0, x, wv0) W2RMW(1, y, wv1) W2RMW(2, z, wv2) W2RMW(3, w, wv3)
#undef W2RMW
        }
      }
      float gp0 = 0.5f * (1.0f + er0) + z10 * expf(-0.5f * z10 * z10) * PDF_CF;
      float gp1 = 0.5f * (1.0f + er1) + z11 * expf(-0.5f * z11 * z11) * PDF_CF;
      gZ1s[m0][c] = sD0 * gp0;
      gZ1s[m1][c] = sD1 * gp1;
    }
    __syncthreads();  // B5 (gZ1s + W2L updates visible)

    // ---- E: W1[:,c] + b1 update (identical across g) ; b2 update ----
    {
      const float ga0 = gZ1s[0][c], ga1 = gZ1s[1][c];
      const float ga2 = gZ1s[2][c], ga3 = gZ1s[3][c];
      b1r = fmaf(-ETA, ((ga0 + ga1) + ga2) + ga3, b1r);
#pragma unroll
      for (int k4 = 0; k4 < 64; k4 += 4) {
        float4 a0 = *(const float4*)&xkL[k4];
        float4 a1 = *(const float4*)&xkL[64 + k4];
        float4 a2 = *(const float4*)&xkL[128 + k4];
        float4 a3 = *(const float4*)&xkL[192 + k4];
#define W1S(J, C)                                             \
  {                                                           \
    float u = a0.C * ga0;                                     \
    u = fmaf(a1.C, ga1, u);                                   \
    u = fmaf(a2.C, ga2, u);                                   \
    u = fmaf(a3.C, ga3, u);                                   \
    w1[k4 + J] = fmaf(-ETA, u, w1[k4 + J]);                   \
  }
        W1S(0, x) W1S(1, y) W1S(2, z) W1S(3, w)
#undef W1S
      }
    }
    if (t < 64) {
      float gb2 = ((gZ2s[0][t] + gZ2s[1][t]) + gZ2s[2][t]) + gZ2s[3][t];
      b2s[t] = fmaf(-ETA, gb2, b2s[t]);
    }

    // ---- F: Z1q rows m0,m1 with updated W1 ; gelu -> X2s ----
    {
      float aq0 = b1r, aq1 = b1r;
      const float* xq0 = &xqL[m0 * 64];
      const float* xq1 = &xqL[m1 * 64];
#pragma unroll
      for (int k4 = 0; k4 < 64; k4 += 4) {
        float4 a0 = *(const float4*)&xq0[k4];
        float4 a1 = *(const float4*)&xq1[k4];
        float w0 = w1[k4], wA = w1[k4 + 1], wB = w1[k4 + 2], wC = w1[k4 + 3];
        aq0 = fmaf(a0.x, w0, aq0); aq0 = fmaf(a0.y, wA, aq0);
        aq0 = fmaf(a0.z, wB, aq0); aq0 = fmaf(a0.w, wC, aq0);
        aq1 = fmaf(a1.x, w0, aq1); aq1 = fmaf(a1.y, wA, aq1);
        aq1 = fmaf(a1.z, wB, aq1); aq1 = fmaf(a1.w, wC, aq1);
      }
      X2s[m0][c] = 0.5f * aq0 * (1.0f + erff(aq0 * ERF_CF));
      X2s[m1][c] = 0.5f * aq1 * (1.0f + erff(aq1 * ERF_CF));
    }
    __syncthreads();  // B6

    // ---- G: Z2q partials with updated W2 ----
    {
      float pp0 = 0, pp1 = 0, pp2 = 0, pp3 = 0;
#pragma unroll
      for (int k4 = 0; k4 < 32; k4 += 4) {
        int kk = kb + k4;
        float4 y0 = *(const float4*)&X2s[0][kk];
        float4 y1 = *(const float4*)&X2s[1][kk];
        float4 y2 = *(const float4*)&X2s[2][kk];
        float4 y3 = *(const float4*)&X2s[3][kk];
        float wv0 = W2L[kk][(lane + kk) & 63];
        float wv1 = W2L[kk + 1][(lane + kk + 1) & 63];
        float wv2 = W2L[kk + 2][(lane + kk + 2) & 63];
        float wv3 = W2L[kk + 3][(lane + kk + 3) & 63];
        pp0 = fmaf(y0.x, wv0, pp0); pp0 = fmaf(y0.y, wv1, pp0);
        pp0 = fmaf(y0.z, wv2, pp0); pp0 = fmaf(y0.w, wv3, pp0);
        pp1 = fmaf(y1.x, wv0, pp1); pp1 = fmaf(y1.y, wv1, pp1);
        pp1 = fmaf(y1.z, wv2, pp1); pp1 = fmaf(y1.w, wv3, pp1);
        pp2 = fmaf(y2.x, wv0, pp2); pp2 = fmaf(y2.y, wv1, pp2);
        pp2 = fmaf(y2.z, wv2, pp2); pp2 = fmaf(y2.w, wv3, pp2);
        pp3 = fmaf(y3.x, wv0, pp3); pp3 = fmaf(y3.y, wv1, pp3);
        pp3 = fmaf(y3.z, wv2, pp3); pp3 = fmaf(y3.w, wv3, pp3);
      }
      redS[w8][0][lane] = pp0;
      redS[w8][1][lane] = pp1;
      redS[w8][2][lane] = pp2;
      redS[w8][3][lane] = pp3;
    }
    __syncthreads();  // B7

    // ---- Gr: reduce + LN fwd + residual + output ----
    if (t < 256) {
      float z2 = b2s[lane];
#pragma unroll
      for (int q = 0; q < 8; ++q) z2 += redS[q][w8][lane];
      float mu = wsum(z2) * (1.0f / 64.0f);
      float dv = z2 - mu;
      float var = wsum(dv * dv) * (1.0f / 64.0f);
      float rstd = rsqrtf(var + 1e-6f);
      float val = lwS[lane] * dv * rstd + lbS[lane] + xqL[w8 * 64 + lane];
      outp[((long)(b * 1024 + n * 4 + w8)) * 256 + h * 64 + lane] = val;
    }
    __syncthreads();  // B8
  }
}

// final (4096,64) @ (64,1) + b
__global__ __launch_bounds__(256) void fc3_kernel(const float* __restrict__ f2,
                                                  const float* __restrict__ w,
                                                  const float* __restrict__ bias,
                                                  float* __restrict__ o) {
  int m = blockIdx.x * 4 + (threadIdx.x >> 6);
  int lane = threadIdx.x & 63;
  float v = f2[m * 64 + lane] * w[lane];
  v = wsum(v);
  if (lane == 0) o[m] = v + bias[0];
}

// ---------------------------------------------------------------------------
extern "C" void kernel_launch(void* const* d_in, const int* in_sizes, int n_in,
                              void* d_out, int out_size, void* d_ws, size_t ws_size,
                              hipStream_t stream) {
  const float* x       = (const float*)d_in[0];
  const float* conv1_w = (const float*)d_in[1];
  const float* conv1_b = (const float*)d_in[2];
  const float* convs_w = (const float*)d_in[3];
  const float* convs_b = (const float*)d_in[4];
  const float* ln_w    = (const float*)d_in[5];
  const float* ln_b    = (const float*)d_in[6];
  const float* wq      = (const float*)d_in[7];
  const float* wk      = (const float*)d_in[8];
  const float* wv      = (const float*)d_in[9];
  const float* wo      = (const float*)d_in[10];
  const float* ttt_W1  = (const float*)d_in[11];
  const float* ttt_b1  = (const float*)d_in[12];
  const float* ttt_W2  = (const float*)d_in[13];
  const float* ttt_b2  = (const float*)d_in[14];
  const float* ttt_lnw = (const float*)d_in[15];
  const float* ttt_lnb = (const float*)d_in[16];
  const float* fc_w    = (const float*)d_in[17];
  const float* fc_b    = (const float*)d_in[18];
  const float* fc2_w   = (const float*)d_in[19];
  const float* fc2_b   = (const float*)d_in[20];
  const float* fc3_w   = (const float*)d_in[21];
  const float* fc3_b   = (const float*)d_in[22];

  float* ws = (float*)d_ws;
  float* wt1  = ws + 0;                       // 16384
  float* wt   = ws + 16384;                   // 1572864
  float* bufA = ws + 1589248;                 // 1050624 (B,L+2,256)
  float* bufB = ws + 2639872;                 // 1050624
  float* sum4 = ws + 3690496;                 // 1048576 (B,L,256)
  float* tln  = ws + 4739072;                 // 1048576
  float* XQ   = ws + 5787648;                 // 1048576 (B,H,L,64)
  float* XK   = ws + 6836224;                 // 1048576
  float* XV   = ws + 7884800;                 // 1048576
  float* tout = ws + 8933376;                 // 1048576
  float* tfull = sum4;
  float* h2    = bufA;
  float* f1    = XQ;
  float* f2    = tout;

  const int M = 4096;
  dim3 blk(256);

  zero_halo<<<16, blk, 0, stream>>>(bufA, bufB);
  prep_w<<<6208, blk, 0, stream>>>(conv1_w, convs_w, wt1, wt);

  // conv1 (1x1) + relu -> bufA (halo store)
  gemm_k<1, 1, 0, 1, 0><<<dim3(64, 4), blk, 0, stream>>>(
      x, wt1, conv1_b, nullptr, bufA, nullptr, M, 256, 64, 64, 0);

  // 8 sequential 3-tap convs, accumulate acts 1,3,5,7 into sum4
  for (int i = 0; i < 8; ++i) {
    const float* in = (i % 2 == 0) ? bufA : bufB;
    float* out = (i % 2 == 0) ? bufB : bufA;
    const float* wp = wt + (size_t)i * 196608;
    const float* bp = convs_b + i * 256;
    if (i == 1)
      gemm_k<1, 1, 0, 1, 1><<<dim3(64, 4), blk, 0, stream>>>(
          in, wp, bp, nullptr, out, sum4, M, 256, 768, 256, 1);
    else if (i == 3 || i == 5 || i == 7)
      gemm_k<1, 1, 0, 1, 2><<<dim3(64, 4), blk, 0, stream>>>(
          in, wp, bp, nullptr, out, sum4, M, 256, 768, 256, 1);
    else
      gemm_k<1, 1, 0, 1, 0><<<dim3(64, 4), blk, 0, stream>>>(
          in, wp, bp, nullptr, out, sum4, M, 256, 768, 256, 1);
  }

  // LN #1
  ln_kernel<<<1024, blk, 0, stream>>>(sum4, tln, ln_w, ln_b, 1e-5f);

  // QKV projections with (B,H,L,64) scatter
  gemm_k<0, 0, 0, 2, 0><<<dim3(64, 4), blk, 0, stream>>>(
      tln, wq, nullptr, nullptr, XQ, nullptr, M, 256, 256, 256, 0);
  gemm_k<0, 0, 0, 2, 0><<<dim3(64, 4), blk, 0, stream>>>(
      tln, wk, nullptr, nullptr, XK, nullptr, M, 256, 256, 256, 0);
  gemm_k<0, 0, 0, 2, 0><<<dim3(64, 4), blk, 0, stream>>>(
      tln, wv, nullptr, nullptr, XV, nullptr, M, 256, 256, 256, 0);

  // TTT scan: 16 chains, 512 threads each
  ttt_kernel<<<16, dim3(512), 0, stream>>>(XQ, XK, XV, ttt_W1, ttt_b1, ttt_W2,
                                           ttt_b2, ttt_lnw, ttt_lnb, tout);

  // x + out@wo  (residual = tln)
  gemm_k<0, 0, 1, 0, 0><<<dim3(64, 4), blk, 0, stream>>>(
      tout, wo, nullptr, tln, tfull, nullptr, M, 256, 256, 256, 0);

  // LN #2
  ln_kernel<<<1024, blk, 0, stream>>>(tfull, h2, ln_w, ln_b, 1e-5f);

  // fc (256->512), fc2 (512->64), fc3 (64->1)
  gemm_k<1, 0, 0, 0, 0><<<dim3(64, 8), blk, 0, stream>>>(
      h2, fc_w, fc_b, nullptr, f1, nullptr, M, 512, 256, 256, 0);
  gemm_k<1, 0, 0, 0, 0><<<dim3(64, 1), blk, 0, stream>>>(
      f1, fc2_w, fc2_b, nullptr, f2, nullptr, M, 64, 512, 512, 0);
  fc3_kernel<<<1024, blk, 0, stream>>>(f2, fc3_w, fc3_b, (float*)d_out);
}

// Round 5
// 3949.636 us; speedup vs baseline: 2.4389x; 2.4389x over previous
//
#include <hip/hip_runtime.h>
#include <hip/hip_bf16.h>

// ResNetTTT. Round 5: TTT step rewritten with MFMA (16x16x32 bf16, split
// hi/lo operands, 3 MFMAs per matmul => ~fp32-grade precision). Weights as
// packed (bf16hi|bf16lo) uint32 masters in LDS, fp32 VALU rank-4 updates.

#define ERF_CF 0.70710678118654752f
#define PDF_CF 0.3989422804014327f
#define ETA 0.025f   // TTT_LR / MB

typedef __attribute__((ext_vector_type(8))) short bfrag;    // 8 bf16 (4 VGPR)
typedef __attribute__((ext_vector_type(4))) float f32x4;

union FB { bfrag v; unsigned short u[8]; };

__device__ __forceinline__ float wsum(float v) {
#pragma unroll
  for (int o = 32; o > 0; o >>= 1) v += __shfl_xor(v, o, 64);
  return v;
}

// split fp32 -> packed (hi bf16 in high16, lo bf16 in low16); hi+lo ~ 2^-17 rel
__device__ __forceinline__ unsigned pack_split(float x) {
  unsigned u = __float_as_uint(x);
  unsigned hb = u & 0xFFFF0000u;
  float lf = x - __uint_as_float(hb);
  return hb | (__float_as_uint(lf) >> 16);
}
__device__ __forceinline__ float unpack_f(unsigned p) {
  return __uint_as_float(p & 0xFFFF0000u) + __uint_as_float(p << 16);
}
__device__ __forceinline__ void frag_packed(const unsigned* p, bfrag& fh, bfrag& fl) {
  uint4 A = *(const uint4*)p;
  uint4 B = *(const uint4*)(p + 4);
  FB H, L;
  H.u[0] = (unsigned short)(A.x >> 16); L.u[0] = (unsigned short)(A.x & 0xFFFFu);
  H.u[1] = (unsigned short)(A.y >> 16); L.u[1] = (unsigned short)(A.y & 0xFFFFu);
  H.u[2] = (unsigned short)(A.z >> 16); L.u[2] = (unsigned short)(A.z & 0xFFFFu);
  H.u[3] = (unsigned short)(A.w >> 16); L.u[3] = (unsigned short)(A.w & 0xFFFFu);
  H.u[4] = (unsigned short)(B.x >> 16); L.u[4] = (unsigned short)(B.x & 0xFFFFu);
  H.u[5] = (unsigned short)(B.y >> 16); L.u[5] = (unsigned short)(B.y & 0xFFFFu);
  H.u[6] = (unsigned short)(B.z >> 16); L.u[6] = (unsigned short)(B.z & 0xFFFFu);
  H.u[7] = (unsigned short)(B.w >> 16); L.u[7] = (unsigned short)(B.w & 0xFFFFu);
  fh = H.v; fl = L.v;
}
__device__ __forceinline__ void frag_zero(bfrag& fh, bfrag& fl) {
  FB Z;
#pragma unroll
  for (int j = 0; j < 8; ++j) Z.u[j] = 0;
  fh = Z.v; fl = Z.v;
}
__device__ __forceinline__ void frag_packed_valid(const unsigned* p, bool valid,
                                                  bfrag& fh, bfrag& fl) {
  if (valid) frag_packed(p, fh, fl);
  else frag_zero(fh, fl);
}
__device__ __forceinline__ void frag_f32v(const float* p, bool valid,
                                          bfrag& fh, bfrag& fl) {
  if (!valid) { frag_zero(fh, fl); return; }
  float av[8];
  *(float4*)&av[0] = *(const float4*)p;
  *(float4*)&av[4] = *(const float4*)(p + 4);
  FB H, L;
#pragma unroll
  for (int j = 0; j < 8; ++j) {
    unsigned u = __float_as_uint(av[j]);
    unsigned hb = u & 0xFFFF0000u;
    H.u[j] = (unsigned short)(u >> 16);
    L.u[j] = (unsigned short)(__float_as_uint(av[j] - __uint_as_float(hb)) >> 16);
  }
  fh = H.v; fl = L.v;
}
__device__ __forceinline__ void frag_gather68(const unsigned* base, bfrag& fh, bfrag& fl) {
  FB H, L;
#pragma unroll
  for (int e = 0; e < 8; ++e) {
    unsigned u = base[e * 68];
    H.u[e] = (unsigned short)(u >> 16);
    L.u[e] = (unsigned short)(u & 0xFFFFu);
  }
  fh = H.v; fl = L.v;
}
__device__ __forceinline__ f32x4 mm3(bfrag ah, bfrag al, bfrag bh, bfrag bl, f32x4 acc) {
  acc = __builtin_amdgcn_mfma_f32_16x16x32_bf16(ah, bh, acc, 0, 0, 0);
  acc = __builtin_amdgcn_mfma_f32_16x16x32_bf16(ah, bl, acc, 0, 0, 0);
  acc = __builtin_amdgcn_mfma_f32_16x16x32_bf16(al, bh, acc, 0, 0, 0);
  return acc;
}

// ---------------------------------------------------------------------------
// prep / zero_halo / gemm_k / ln_kernel / fc3_kernel (unchanged)
// ---------------------------------------------------------------------------
__global__ void prep_w(const float* __restrict__ c1w, const float* __restrict__ cw,
                       float* __restrict__ wt1, float* __restrict__ wt) {
  int id = blockIdx.x * 256 + threadIdx.x;
  if (id < 16384) {
    int ci = id >> 8, co = id & 255;
    wt1[id] = c1w[co * 64 + ci];
  }
  int id2 = id - 16384;
  if (id2 >= 0 && id2 < 1572864) {
    int cv = id2 / 196608;
    int r = id2 - cv * 196608;
    int k = r >> 8, co = r & 255;
    int tt = k >> 8, ci = k & 255;
    wt[id2] = cw[((cv * 256 + co) * 256 + ci) * 3 + tt];
  }
}

__global__ void zero_halo(float* __restrict__ bufA, float* __restrict__ bufB) {
  int id = blockIdx.x * 256 + threadIdx.x;
  int c = id & 255;
  int row = (id >> 8) & 1;
  int b = (id >> 9) & 3;
  float* p = (id >> 11) ? bufB : bufA;
  p[(b * 1026 + row * 1025) * 256 + c] = 0.0f;
}

template <int BIAS, int RELU, int RES, int OST, int ACC>
__global__ __launch_bounds__(256) void gemm_k(
    const float* __restrict__ A, const float* __restrict__ Wt,
    const float* __restrict__ bias, const float* __restrict__ res,
    float* __restrict__ out, float* __restrict__ accp,
    int M, int N, int K, int lda, int haloA) {
  __shared__ float As[16][68];
  __shared__ float Bs[16][64];
  const int tid = threadIdx.x;
  const int bm = blockIdx.x * 64, bn = blockIdx.y * 64;
  const int tx = tid & 15, ty = tid >> 4;
  float acc[4][4] = {};

  for (int k0 = 0; k0 < K; k0 += 16) {
#pragma unroll
    for (int i = 0; i < 4; ++i) {
      int idx = tid + i * 256;
      int kk = idx & 15, mm = idx >> 4;
      int m = bm + mm;
      int rb = m * lda + (haloA ? ((m >> 10) << 9) : 0);
      As[kk][mm] = A[rb + k0 + kk];
    }
#pragma unroll
    for (int i = 0; i < 4; ++i) {
      int idx = tid + i * 256;
      int nn = idx & 63, kk = idx >> 6;
      Bs[kk][nn] = Wt[(k0 + kk) * N + bn + nn];
    }
    __syncthreads();
#pragma unroll
    for (int kk = 0; kk < 16; ++kk) {
      float4 av = *(const float4*)&As[kk][ty * 4];
      float4 bv = *(const float4*)&Bs[kk][tx * 4];
      float aa[4] = {av.x, av.y, av.z, av.w};
      float bb[4] = {bv.x, bv.y, bv.z, bv.w};
#pragma unroll
      for (int i = 0; i < 4; ++i)
#pragma unroll
        for (int j = 0; j < 4; ++j) acc[i][j] = fmaf(aa[i], bb[j], acc[i][j]);
    }
    __syncthreads();
  }

  const int n0 = bn + tx * 4;
#pragma unroll
  for (int i = 0; i < 4; ++i) {
    int m = bm + ty * 4 + i;
    int b_ = m >> 10, l = m & 1023;
    float v[4];
#pragma unroll
    for (int j = 0; j < 4; ++j) {
      float x = acc[i][j];
      if constexpr (BIAS) x += bias[n0 + j];
      if constexpr (RELU) x = fmaxf(x, 0.0f);
      if constexpr (RES) x += res[m * N + n0 + j];
      v[j] = x;
    }
    float4 vv = make_float4(v[0], v[1], v[2], v[3]);
    if constexpr (OST == 0) {
      *(float4*)&out[m * N + n0] = vv;
    } else if constexpr (OST == 1) {
      *(float4*)&out[(b_ * 1026 + l + 1) * 256 + n0] = vv;
    } else {
      int hq = n0 >> 6;
      int oidx = (((b_ * 4 + hq) * 1024 + l) << 6) + (n0 & 63);
      *(float4*)&out[oidx] = vv;
    }
    if constexpr (ACC == 1) {
      *(float4*)&accp[m * 256 + n0] = vv;
    } else if constexpr (ACC == 2) {
      float4 s = *(const float4*)&accp[m * 256 + n0];
      s.x += vv.x; s.y += vv.y; s.z += vv.z; s.w += vv.w;
      *(float4*)&accp[m * 256 + n0] = s;
    }
  }
}

__global__ __launch_bounds__(256) void ln_kernel(const float* __restrict__ in,
                                                 float* __restrict__ o,
                                                 const float* __restrict__ w,
                                                 const float* __restrict__ bb,
                                                 float eps) {
  int row = blockIdx.x * 4 + (threadIdx.x >> 6);
  int l = threadIdx.x & 63;
  float4 v = ((const float4*)(in + (long)row * 256))[l];
  float s = wsum(v.x + v.y + v.z + v.w);
  float mu = s * (1.0f / 256.0f);
  float dx = v.x - mu, dy = v.y - mu, dz = v.z - mu, dw = v.w - mu;
  float ss = wsum(dx * dx + dy * dy + dz * dz + dw * dw);
  float rstd = rsqrtf(ss * (1.0f / 256.0f) + eps);
  float4 wv = ((const float4*)w)[l];
  float4 bv = ((const float4*)bb)[l];
  float4 r;
  r.x = wv.x * dx * rstd + bv.x;
  r.y = wv.y * dy * rstd + bv.y;
  r.z = wv.z * dz * rstd + bv.z;
  r.w = wv.w * dw * rstd + bv.w;
  ((float4*)(o + (long)row * 256))[l] = r;
}

// ---------------------------------------------------------------------------
// TTT scan via MFMA. 1 block (256 thr, 4 waves) per (b,h) chain.
// lane: a = lane&15 (A-row / B-col / D-col), g = lane>>4 (k-slot group).
// k-bijection kappa(g,j) = kc*32 + g*8 + j used consistently for A and B.
// LDS: W1P[c][k] packed-pair (c 0..255, k 0..63, stride 68),
//      W2P[k][j] packed-pair (k 0..255, j 0..63, stride 68).
// ---------------------------------------------------------------------------
__global__ __launch_bounds__(256, 1) void ttt_mfma(
    const float* __restrict__ XQ, const float* __restrict__ XK,
    const float* __restrict__ XV, const float* __restrict__ W1i,
    const float* __restrict__ B1i, const float* __restrict__ W2i,
    const float* __restrict__ B2i, const float* __restrict__ LNW,
    const float* __restrict__ LNB, float* __restrict__ outp) {
  extern __shared__ char smem_raw[];
  unsigned* W1P = (unsigned*)smem_raw;        // 256*68
  unsigned* W2P = W1P + 256 * 68;             // 256*68
  float* xkL = (float*)(W2P + 256 * 68);      // 256
  float* xvL = xkL + 256;                     // 256
  float* xqL = xvL + 256;                     // 256
  float* Z1L = xqL + 256;                     // [4][256]: Z1 raw -> gZ1 f32 -> Z1q raw
  unsigned* X2P = (unsigned*)(Z1L + 1024);    // [4][256] packed X2 / X2q
  unsigned* GPP = X2P + 1024;                 // [4][256] packed gelu-grad
  float* Z2L = (float*)(GPP + 1024);          // [4][64]: Z2 -> gZ2 f32 -> Z2q
  unsigned* gZ2P = (unsigned*)(Z2L + 256);    // [4][64] packed gZ2
  float* b1L = (float*)(gZ2P + 256);          // 256
  float* b2L = b1L + 256;                     // 64
  float* lwL = b2L + 64;                      // 64
  float* lbL = lwL + 64;                      // 64

  const int bh = blockIdx.x, b = bh >> 2, h = bh & 3;
  const int t = threadIdx.x, lane = t & 63, w = t >> 6;
  const int a = lane & 15, g = lane >> 4;
  const bool rowv = (a < 4);
  const bool g0 = (g == 0);

  // ---- init weights / biases ----
  for (int i = 0; i < 64; ++i) {
    int idx = i * 256 + t;
    int k = idx >> 8, c = idx & 255;
    W1P[c * 68 + k] = pack_split(W1i[(h * 64 + k) * 256 + c]);
  }
  for (int i = 0; i < 64; ++i) {
    int idx = i * 256 + t;
    int k = idx >> 6, j = idx & 63;
    W2P[k * 68 + j] = pack_split(W2i[(h * 256 + k) * 64 + j]);
  }
  b1L[t] = B1i[h * 256 + t];
  if (t < 64) {
    b2L[t] = B2i[h * 64 + t];
    lwL[t] = LNW[h * 64 + t];
    lbL[t] = LNB[h * 64 + t];
  }

  const long chain = (long)bh * 65536;
  float rk = XK[chain + t], rvv = XV[chain + t], rq = XQ[chain + t];
  __syncthreads();

  for (int n = 0; n < 256; ++n) {
    xkL[t] = rk; xvL[t] = rvv; xqL[t] = rq;
    __syncthreads();  // B1

    // ---- S1: Z1 = xk @ W1 + b1 (K=64, 16 n-tiles over 4 waves) ----
    {
      f32x4 acc[4];
#pragma unroll
      for (int i = 0; i < 4; ++i) {
        float bv = b1L[(4 * w + i) * 16 + a];
        acc[i] = (f32x4){bv, bv, bv, bv};
      }
#pragma unroll
      for (int kc = 0; kc < 2; ++kc) {
        bfrag ah, al;
        frag_f32v(&xkL[a * 64 + kc * 32 + g * 8], rowv, ah, al);
#pragma unroll
        for (int i = 0; i < 4; ++i) {
          int c = (4 * w + i) * 16 + a;
          bfrag bh_, bl_;
          frag_packed(&W1P[c * 68 + kc * 32 + g * 8], bh_, bl_);
          acc[i] = mm3(ah, al, bh_, bl_, acc[i]);
        }
      }
      if (g0) {
#pragma unroll
        for (int i = 0; i < 4; ++i) {
          int c = (4 * w + i) * 16 + a;
#pragma unroll
          for (int q = 0; q < 4; ++q) Z1L[q * 256 + c] = acc[i][q];
        }
      }
    }
    __syncthreads();  // B2

    // ---- geluA: X2 = gelu(Z1), gp = gelu'(Z1) ----
    {
      int m = t >> 6, c0 = (t & 63) * 4;
      float4 z4 = *(const float4*)&Z1L[m * 256 + c0];
      float zz[4] = {z4.x, z4.y, z4.z, z4.w};
      unsigned xo[4], go[4];
#pragma unroll
      for (int j = 0; j < 4; ++j) {
        float z = zz[j];
        float er = erff(z * ERF_CF);
        float x2 = 0.5f * z * (1.0f + er);
        float gp = 0.5f * (1.0f + er) + z * expf(-0.5f * z * z) * PDF_CF;
        xo[j] = pack_split(x2);
        go[j] = pack_split(gp);
      }
      *(uint4*)&X2P[m * 256 + c0] = make_uint4(xo[0], xo[1], xo[2], xo[3]);
      *(uint4*)&GPP[m * 256 + c0] = make_uint4(go[0], go[1], go[2], go[3]);
    }
    __syncthreads();  // B3

    // ---- S2: Z2 = X2 @ W2 + b2 (K=256; wave w -> cols 16w..16w+15) ----
    {
      float bv = b2L[w * 16 + a];
      f32x4 acc = (f32x4){bv, bv, bv, bv};
#pragma unroll
      for (int kc = 0; kc < 8; ++kc) {
        bfrag ah, al;
        frag_packed_valid(&X2P[a * 256 + kc * 32 + g * 8], rowv, ah, al);
        bfrag bh_, bl_;
        frag_gather68(&W2P[(kc * 32 + g * 8) * 68 + (w * 16 + a)], bh_, bl_);
        acc = mm3(ah, al, bh_, bl_, acc);
      }
      if (g0) {
#pragma unroll
        for (int q = 0; q < 4; ++q) Z2L[q * 64 + w * 16 + a] = acc[q];
      }
    }
    __syncthreads();  // B4

    // ---- LN-l2-bwd over rows (row m = w, col = lane) ----
    {
      int j = lane;
      float z2 = Z2L[w * 64 + j];
      float mu = wsum(z2) * (1.0f / 64.0f);
      float dv = z2 - mu;
      float var = wsum(dv * dv) * (1.0f / 64.0f);
      float stdv = sqrtf(var + 1e-6f);
      float zh = dv / stdv;
      float lw = lwL[j], lb = lbL[j];
      float tgt = xvL[w * 64 + j] - xkL[w * 64 + j];
      float gg = lw * (lw * zh + lb - tgt);
      float gs = wsum(gg) * (1.0f / 64.0f);
      float gzs = wsum(gg * zh) * (1.0f / 64.0f);
      float gz2 = (gg - gs - zh * gzs) / stdv;
      gZ2P[w * 64 + j] = pack_split(gz2);
      Z2L[w * 64 + j] = gz2;  // fp32 copy (same thread, safe)
    }
    __syncthreads();  // B5

    // prefetch next step's inputs
    if (n + 1 < 256) {
      long nb = chain + (long)(n + 1) * 256;
      rk = XK[nb + t]; rvv = XV[nb + t]; rq = XQ[nb + t];
    }

    // ---- S3: gZ1 = (gZ2 @ W2^T) * gp (K=64 over j) ----
    {
      f32x4 acc[4];
#pragma unroll
      for (int i = 0; i < 4; ++i) acc[i] = (f32x4){0.f, 0.f, 0.f, 0.f};
#pragma unroll
      for (int kc = 0; kc < 2; ++kc) {
        bfrag ah, al;
        frag_packed_valid(&gZ2P[a * 64 + kc * 32 + g * 8], rowv, ah, al);
#pragma unroll
        for (int i = 0; i < 4; ++i) {
          int c = (4 * w + i) * 16 + a;
          bfrag bh_, bl_;
          frag_packed(&W2P[c * 68 + kc * 32 + g * 8], bh_, bl_);  // W2^T row c
          acc[i] = mm3(ah, al, bh_, bl_, acc[i]);
        }
      }
      if (g0) {
#pragma unroll
        for (int i = 0; i < 4; ++i) {
          int c = (4 * w + i) * 16 + a;
#pragma unroll
          for (int q = 0; q < 4; ++q) {
            float gp = unpack_f(GPP[q * 256 + c]);
            Z1L[q * 256 + c] = acc[i][q] * gp;  // gZ1 fp32
          }
        }
      }
    }
    __syncthreads();  // B6

    // ---- UPD: W1 (col t), W2 (row t), b1, b2 in fp32 ----
    {
      float ga0 = Z1L[t], ga1 = Z1L[256 + t], ga2 = Z1L[512 + t], ga3 = Z1L[768 + t];
      b1L[t] -= ETA * (((ga0 + ga1) + ga2) + ga3);
#pragma unroll
      for (int k4 = 0; k4 < 64; k4 += 4) {
        float4 x0 = *(const float4*)&xkL[k4];
        float4 x1 = *(const float4*)&xkL[64 + k4];
        float4 x2v = *(const float4*)&xkL[128 + k4];
        float4 x3 = *(const float4*)&xkL[192 + k4];
        uint4 wp = *(uint4*)&W1P[t * 68 + k4];
#define W1U(WC, XC)                                                        \
  {                                                                        \
    float u = x0.XC * ga0;                                                 \
    u = fmaf(x1.XC, ga1, u);                                               \
    u = fmaf(x2v.XC, ga2, u);                                              \
    u = fmaf(x3.XC, ga3, u);                                               \
    float f = unpack_f(wp.WC) - ETA * u;                                   \
    wp.WC = pack_split(f);                                                 \
  }
        W1U(x, x) W1U(y, y) W1U(z, z) W1U(w, w)
#undef W1U
        *(uint4*)&W1P[t * 68 + k4] = wp;
      }
      float xr0 = unpack_f(X2P[t]), xr1 = unpack_f(X2P[256 + t]);
      float xr2 = unpack_f(X2P[512 + t]), xr3 = unpack_f(X2P[768 + t]);
#pragma unroll
      for (int j4 = 0; j4 < 64; j4 += 4) {
        float4 G0 = *(const float4*)&Z2L[j4];
        float4 G1 = *(const float4*)&Z2L[64 + j4];
        float4 G2 = *(const float4*)&Z2L[128 + j4];
        float4 G3 = *(const float4*)&Z2L[192 + j4];
        uint4 wp = *(uint4*)&W2P[t * 68 + j4];
#define W2U(WC, XC)                                                        \
  {                                                                        \
    float u = xr0 * G0.XC;                                                 \
    u = fmaf(xr1, G1.XC, u);                                               \
    u = fmaf(xr2, G2.XC, u);                                               \
    u = fmaf(xr3, G3.XC, u);                                               \
    float f = unpack_f(wp.WC) - ETA * u;                                   \
    wp.WC = pack_split(f);                                                 \
  }
        W2U(x, x) W2U(y, y) W2U(z, z) W2U(w, w)
#undef W2U
        *(uint4*)&W2P[t * 68 + j4] = wp;
      }
      if (t < 64) {
        float s = Z2L[t] + Z2L[64 + t] + Z2L[128 + t] + Z2L[192 + t];
        b2L[t] -= ETA * s;
      }
    }
    __syncthreads();  // B7

    // ---- S6: Z1q = xq @ W1' + b1' ----
    {
      f32x4 acc[4];
#pragma unroll
      for (int i = 0; i < 4; ++i) {
        float bv = b1L[(4 * w + i) * 16 + a];
        acc[i] = (f32x4){bv, bv, bv, bv};
      }
#pragma unroll
      for (int kc = 0; kc < 2; ++kc) {
        bfrag ah, al;
        frag_f32v(&xqL[a * 64 + kc * 32 + g * 8], rowv, ah, al);
#pragma unroll
        for (int i = 0; i < 4; ++i) {
          int c = (4 * w + i) * 16 + a;
          bfrag bh_, bl_;
          frag_packed(&W1P[c * 68 + kc * 32 + g * 8], bh_, bl_);
          acc[i] = mm3(ah, al, bh_, bl_, acc[i]);
        }
      }
      if (g0) {
#pragma unroll
        for (int i = 0; i < 4; ++i) {
          int c = (4 * w + i) * 16 + a;
#pragma unroll
          for (int q = 0; q < 4; ++q) Z1L[q * 256 + c] = acc[i][q];
        }
      }
    }
    __syncthreads();  // B8

    // ---- geluB: X2q = gelu(Z1q) ----
    {
      int m = t >> 6, c0 = (t & 63) * 4;
      float4 z4 = *(const float4*)&Z1L[m * 256 + c0];
      float zz[4] = {z4.x, z4.y, z4.z, z4.w};
      unsigned xo[4];
#pragma unroll
      for (int j = 0; j < 4; ++j) {
        float z = zz[j];
        float er = erff(z * ERF_CF);
        xo[j] = pack_split(0.5f * z * (1.0f + er));
      }
      *(uint4*)&X2P[m * 256 + c0] = make_uint4(xo[0], xo[1], xo[2], xo[3]);
    }
    __syncthreads();  // B9

    // ---- S7: Z2q = X2q @ W2' + b2' ----
    {
      float bv = b2L[w * 16 + a];
      f32x4 acc = (f32x4){bv, bv, bv, bv};
#pragma unroll
      for (int kc = 0; kc < 8; ++kc) {
        bfrag ah, al;
        frag_packed_valid(&X2P[a * 256 + kc * 32 + g * 8], rowv, ah, al);
        bfrag bh_, bl_;
        frag_gather68(&W2P[(kc * 32 + g * 8) * 68 + (w * 16 + a)], bh_, bl_);
        acc = mm3(ah, al, bh_, bl_, acc);
      }
      if (g0) {
#pragma unroll
        for (int q = 0; q < 4; ++q) Z2L[q * 64 + w * 16 + a] = acc[q];
      }
    }
    __syncthreads();  // B10

    // ---- LN fwd + residual + output ----
    {
      int j = lane;
      float z = Z2L[w * 64 + j];
      float mu = wsum(z) * (1.0f / 64.0f);
      float dv = z - mu;
      float var = wsum(dv * dv) * (1.0f / 64.0f);
      float rstd = rsqrtf(var + 1e-6f);
      float val = lwL[j] * dv * rstd + lbL[j] + xqL[w * 64 + j];
      outp[((long)(b * 1024 + n * 4 + w)) * 256 + h * 64 + j] = val;
    }
    __syncthreads();  // B11
  }
}

// final (4096,64) @ (64,1) + b
__global__ __launch_bounds__(256) void fc3_kernel(const float* __restrict__ f2,
                                                  const float* __restrict__ w,
                                                  const float* __restrict__ bias,
                                                  float* __restrict__ o) {
  int m = blockIdx.x * 4 + (threadIdx.x >> 6);
  int lane = threadIdx.x & 63;
  float v = f2[m * 64 + lane] * w[lane];
  v = wsum(v);
  if (lane == 0) o[m] = v + bias[0];
}

// ---------------------------------------------------------------------------
extern "C" void kernel_launch(void* const* d_in, const int* in_sizes, int n_in,
                              void* d_out, int out_size, void* d_ws, size_t ws_size,
                              hipStream_t stream) {
  const float* x       = (const float*)d_in[0];
  const float* conv1_w = (const float*)d_in[1];
  const float* conv1_b = (const float*)d_in[2];
  const float* convs_w = (const float*)d_in[3];
  const float* convs_b = (const float*)d_in[4];
  const float* ln_w    = (const float*)d_in[5];
  const float* ln_b    = (const float*)d_in[6];
  const float* wq      = (const float*)d_in[7];
  const float* wk      = (const float*)d_in[8];
  const float* wv      = (const float*)d_in[9];
  const float* wo      = (const float*)d_in[10];
  const float* ttt_W1  = (const float*)d_in[11];
  const float* ttt_b1  = (const float*)d_in[12];
  const float* ttt_W2  = (const float*)d_in[13];
  const float* ttt_b2  = (const float*)d_in[14];
  const float* ttt_lnw = (const float*)d_in[15];
  const float* ttt_lnb = (const float*)d_in[16];
  const float* fc_w    = (const float*)d_in[17];
  const float* fc_b    = (const float*)d_in[18];
  const float* fc2_w   = (const float*)d_in[19];
  const float* fc2_b   = (const float*)d_in[20];
  const float* fc3_w   = (const float*)d_in[21];
  const float* fc3_b   = (const float*)d_in[22];

  float* ws = (float*)d_ws;
  float* wt1  = ws + 0;
  float* wt   = ws + 16384;
  float* bufA = ws + 1589248;
  float* bufB = ws + 2639872;
  float* sum4 = ws + 3690496;
  float* tln  = ws + 4739072;
  float* XQ   = ws + 5787648;
  float* XK   = ws + 6836224;
  float* XV   = ws + 7884800;
  float* tout = ws + 8933376;
  float* tfull = sum4;
  float* h2    = bufA;
  float* f1    = XQ;
  float* f2    = tout;

  const int M = 4096;
  dim3 blk(256);

  zero_halo<<<16, blk, 0, stream>>>(bufA, bufB);
  prep_w<<<6208, blk, 0, stream>>>(conv1_w, convs_w, wt1, wt);

  gemm_k<1, 1, 0, 1, 0><<<dim3(64, 4), blk, 0, stream>>>(
      x, wt1, conv1_b, nullptr, bufA, nullptr, M, 256, 64, 64, 0);

  for (int i = 0; i < 8; ++i) {
    const float* in = (i % 2 == 0) ? bufA : bufB;
    float* out = (i % 2 == 0) ? bufB : bufA;
    const float* wp = wt + (size_t)i * 196608;
    const float* bp = convs_b + i * 256;
    if (i == 1)
      gemm_k<1, 1, 0, 1, 1><<<dim3(64, 4), blk, 0, stream>>>(
          in, wp, bp, nullptr, out, sum4, M, 256, 768, 256, 1);
    else if (i == 3 || i == 5 || i == 7)
      gemm_k<1, 1, 0, 1, 2><<<dim3(64, 4), blk, 0, stream>>>(
          in, wp, bp, nullptr, out, sum4, M, 256, 768, 256, 1);
    else
      gemm_k<1, 1, 0, 1, 0><<<dim3(64, 4), blk, 0, stream>>>(
          in, wp, bp, nullptr, out, sum4, M, 256, 768, 256, 1);
  }

  ln_kernel<<<1024, blk, 0, stream>>>(sum4, tln, ln_w, ln_b, 1e-5f);

  gemm_k<0, 0, 0, 2, 0><<<dim3(64, 4), blk, 0, stream>>>(
      tln, wq, nullptr, nullptr, XQ, nullptr, M, 256, 256, 256, 0);
  gemm_k<0, 0, 0, 2, 0><<<dim3(64, 4), blk, 0, stream>>>(
      tln, wk, nullptr, nullptr, XK, nullptr, M, 256, 256, 256, 0);
  gemm_k<0, 0, 0, 2, 0><<<dim3(64, 4), blk, 0, stream>>>(
      tln, wv, nullptr, nullptr, XV, nullptr, M, 256, 256, 256, 0);

  // TTT scan (MFMA): 16 chains, 256 threads, ~155KB dynamic LDS
  const int TTT_LDS = (256 * 68 * 2 + 256 * 3 + 1024 * 3 + 256 * 2 + 256 + 64 * 3) * 4;
  (void)hipFuncSetAttribute((const void*)ttt_mfma,
                            hipFuncAttributeMaxDynamicSharedMemorySize, TTT_LDS);
  ttt_mfma<<<16, dim3(256), TTT_LDS, stream>>>(XQ, XK, XV, ttt_W1, ttt_b1,
                                               ttt_W2, ttt_b2, ttt_lnw, ttt_lnb,
                                               tout);

  gemm_k<0, 0, 1, 0, 0><<<dim3(64, 4), blk, 0, stream>>>(
      tout, wo, nullptr, tln, tfull, nullptr, M, 256, 256, 256, 0);

  ln_kernel<<<1024, blk, 0, stream>>>(tfull, h2, ln_w, ln_b, 1e-5f);

  gemm_k<1, 0, 0, 0, 0><<<dim3(64, 8), blk, 0, stream>>>(
      h2, fc_w, fc_b, nullptr, f1, nullptr, M, 512, 256, 256, 0);
  gemm_k<1, 0, 0, 0, 0><<<dim3(64, 1), blk, 0, stream>>>(
      f1, fc2_w, fc2_b, nullptr, f2, nullptr, M, 64, 512, 512, 0);
  fc3_kernel<<<1024, blk, 0, stream>>>(f2, fc3_w, fc3_b, (float*)d_out);
}

// Round 6
// 3780.744 us; speedup vs baseline: 2.5478x; 1.0447x over previous
//
#include <hip/hip_runtime.h>
#include <hip/hip_bf16.h>

// ResNetTTT. Round 6: TTT MFMA kernel restructured:
//  - hi/lo bf16 stored as SEPARATE ushort planes -> every MFMA fragment is one
//    aligned ds_read_b128 (no pack/unpack VALU, no gathers)
//  - W2^T plane copy for Z2/Z2q B-operand (kills gather68 4-way conflicts)
//  - W1 lives in registers as distributed B-fragments (in-register rank-4 upd)
//  - 512 threads (8 waves, 2/SIMD), split-K Z2 with 2-way redS combine,
//    prefetch on waves 4-7 during LN phases.

#define ERF_CF 0.70710678118654752f
#define PDF_CF 0.3989422804014327f
#define ETA 0.025f   // TTT_LR / MB

typedef __attribute__((ext_vector_type(8))) short bfrag;    // 8 bf16 (4 VGPR)
typedef __attribute__((ext_vector_type(4))) float f32x4;

union FB { bfrag v; unsigned short u[8]; unsigned d[4]; };

__device__ __forceinline__ float wsum(float v) {
#pragma unroll
  for (int o = 32; o > 0; o >>= 1) v += __shfl_xor(v, o, 64);
  return v;
}

// split fp32 -> (hi bf16 | lo bf16) packed dword
__device__ __forceinline__ unsigned pack_split(float x) {
  unsigned u = __float_as_uint(x);
  unsigned hb = u & 0xFFFF0000u;
  float lf = x - __uint_as_float(hb);
  return hb | (__float_as_uint(lf) >> 16);
}
__device__ __forceinline__ float uns(unsigned short hs, unsigned short ls) {
  return __uint_as_float((unsigned)hs << 16) + __uint_as_float((unsigned)ls << 16);
}
__device__ __forceinline__ float fb_el(const FB& H, const FB& L, int e) {
  return __uint_as_float((unsigned)H.u[e] << 16) +
         __uint_as_float((unsigned)L.u[e] << 16);
}
__device__ __forceinline__ void split2(float f, unsigned short& hs, unsigned short& ls) {
  unsigned u = __float_as_uint(f);
  unsigned hb = u & 0xFFFF0000u;
  hs = (unsigned short)(u >> 16);
  ls = (unsigned short)(__float_as_uint(f - __uint_as_float(hb)) >> 16);
}
__device__ __forceinline__ f32x4 mm3(bfrag ah, bfrag al, bfrag bh, bfrag bl, f32x4 acc) {
  acc = __builtin_amdgcn_mfma_f32_16x16x32_bf16(ah, bh, acc, 0, 0, 0);
  acc = __builtin_amdgcn_mfma_f32_16x16x32_bf16(ah, bl, acc, 0, 0, 0);
  acc = __builtin_amdgcn_mfma_f32_16x16x32_bf16(al, bh, acc, 0, 0, 0);
  return acc;
}

// ---------------------------------------------------------------------------
// prep / zero_halo / gemm_k / ln_kernel / fc3_kernel (unchanged)
// ---------------------------------------------------------------------------
__global__ void prep_w(const float* __restrict__ c1w, const float* __restrict__ cw,
                       float* __restrict__ wt1, float* __restrict__ wt) {
  int id = blockIdx.x * 256 + threadIdx.x;
  if (id < 16384) {
    int ci = id >> 8, co = id & 255;
    wt1[id] = c1w[co * 64 + ci];
  }
  int id2 = id - 16384;
  if (id2 >= 0 && id2 < 1572864) {
    int cv = id2 / 196608;
    int r = id2 - cv * 196608;
    int k = r >> 8, co = r & 255;
    int tt = k >> 8, ci = k & 255;
    wt[id2] = cw[((cv * 256 + co) * 256 + ci) * 3 + tt];
  }
}

__global__ void zero_halo(float* __restrict__ bufA, float* __restrict__ bufB) {
  int id = blockIdx.x * 256 + threadIdx.x;
  int c = id & 255;
  int row = (id >> 8) & 1;
  int b = (id >> 9) & 3;
  float* p = (id >> 11) ? bufB : bufA;
  p[(b * 1026 + row * 1025) * 256 + c] = 0.0f;
}

template <int BIAS, int RELU, int RES, int OST, int ACC>
__global__ __launch_bounds__(256) void gemm_k(
    const float* __restrict__ A, const float* __restrict__ Wt,
    const float* __restrict__ bias, const float* __restrict__ res,
    float* __restrict__ out, float* __restrict__ accp,
    int M, int N, int K, int lda, int haloA) {
  __shared__ float As[16][68];
  __shared__ float Bs[16][64];
  const int tid = threadIdx.x;
  const int bm = blockIdx.x * 64, bn = blockIdx.y * 64;
  const int tx = tid & 15, ty = tid >> 4;
  float acc[4][4] = {};

  for (int k0 = 0; k0 < K; k0 += 16) {
#pragma unroll
    for (int i = 0; i < 4; ++i) {
      int idx = tid + i * 256;
      int kk = idx & 15, mm = idx >> 4;
      int m = bm + mm;
      int rb = m * lda + (haloA ? ((m >> 10) << 9) : 0);
      As[kk][mm] = A[rb + k0 + kk];
    }
#pragma unroll
    for (int i = 0; i < 4; ++i) {
      int idx = tid + i * 256;
      int nn = idx & 63, kk = idx >> 6;
      Bs[kk][nn] = Wt[(k0 + kk) * N + bn + nn];
    }
    __syncthreads();
#pragma unroll
    for (int kk = 0; kk < 16; ++kk) {
      float4 av = *(const float4*)&As[kk][ty * 4];
      float4 bv = *(const float4*)&Bs[kk][tx * 4];
      float aa[4] = {av.x, av.y, av.z, av.w};
      float bb[4] = {bv.x, bv.y, bv.z, bv.w};
#pragma unroll
      for (int i = 0; i < 4; ++i)
#pragma unroll
        for (int j = 0; j < 4; ++j) acc[i][j] = fmaf(aa[i], bb[j], acc[i][j]);
    }
    __syncthreads();
  }

  const int n0 = bn + tx * 4;
#pragma unroll
  for (int i = 0; i < 4; ++i) {
    int m = bm + ty * 4 + i;
    int b_ = m >> 10, l = m & 1023;
    float v[4];
#pragma unroll
    for (int j = 0; j < 4; ++j) {
      float x = acc[i][j];
      if constexpr (BIAS) x += bias[n0 + j];
      if constexpr (RELU) x = fmaxf(x, 0.0f);
      if constexpr (RES) x += res[m * N + n0 + j];
      v[j] = x;
    }
    float4 vv = make_float4(v[0], v[1], v[2], v[3]);
    if constexpr (OST == 0) {
      *(float4*)&out[m * N + n0] = vv;
    } else if constexpr (OST == 1) {
      *(float4*)&out[(b_ * 1026 + l + 1) * 256 + n0] = vv;
    } else {
      int hq = n0 >> 6;
      int oidx = (((b_ * 4 + hq) * 1024 + l) << 6) + (n0 & 63);
      *(float4*)&out[oidx] = vv;
    }
    if constexpr (ACC == 1) {
      *(float4*)&accp[m * 256 + n0] = vv;
    } else if constexpr (ACC == 2) {
      float4 s = *(const float4*)&accp[m * 256 + n0];
      s.x += vv.x; s.y += vv.y; s.z += vv.z; s.w += vv.w;
      *(float4*)&accp[m * 256 + n0] = s;
    }
  }
}

__global__ __launch_bounds__(256) void ln_kernel(const float* __restrict__ in,
                                                 float* __restrict__ o,
                                                 const float* __restrict__ w,
                                                 const float* __restrict__ bb,
                                                 float eps) {
  int row = blockIdx.x * 4 + (threadIdx.x >> 6);
  int l = threadIdx.x & 63;
  float4 v = ((const float4*)(in + (long)row * 256))[l];
  float s = wsum(v.x + v.y + v.z + v.w);
  float mu = s * (1.0f / 256.0f);
  float dx = v.x - mu, dy = v.y - mu, dz = v.z - mu, dw = v.w - mu;
  float rstd = rsqrtf(wsum(dx * dx + dy * dy + dz * dz + dw * dw) * (1.0f / 256.0f) + eps);
  float4 wv = ((const float4*)w)[l];
  float4 bv = ((const float4*)bb)[l];
  float4 r;
  r.x = wv.x * dx * rstd + bv.x;
  r.y = wv.y * dy * rstd + bv.y;
  r.z = wv.z * dz * rstd + bv.z;
  r.w = wv.w * dw * rstd + bv.w;
  ((float4*)(o + (long)row * 256))[l] = r;
}

// ---------------------------------------------------------------------------
// TTT scan via MFMA, 512 threads (8 waves, 2/SIMD) per (b,h) chain.
// lane: a = lane&15 (A-row / B-col / D-col), g = lane>>4 (k-slot group).
// Wave w8: S1/S3/S6 output cols c0,c1 = (2*w8+{0,1})*16+a;
//          S2/S7 tile = w8>>1 (cols tile*16+a), kh = w8&1 (K half).
// ---------------------------------------------------------------------------
__global__ __launch_bounds__(512, 2) void ttt_mfma(
    const float* __restrict__ XQ, const float* __restrict__ XK,
    const float* __restrict__ XV, const float* __restrict__ W1i,
    const float* __restrict__ B1i, const float* __restrict__ W2i,
    const float* __restrict__ B2i, const float* __restrict__ LNW,
    const float* __restrict__ LNB, float* __restrict__ outp) {
  extern __shared__ char smem[];
  unsigned short* W2Hp  = (unsigned short*)smem;   // [256][72]
  unsigned short* W2Lp  = W2Hp + 256 * 72;
  unsigned short* W2THp = W2Lp + 256 * 72;         // [64][264]
  unsigned short* W2TLp = W2THp + 64 * 264;
  unsigned short* X2Hp  = W2TLp + 64 * 264;        // [4][264]
  unsigned short* X2Lp  = X2Hp + 4 * 264;
  unsigned short* xkHp  = X2Lp + 4 * 264;          // [4][72]
  unsigned short* xkLp  = xkHp + 4 * 72;
  unsigned short* xqHp  = xkLp + 4 * 72;
  unsigned short* xqLp  = xqHp + 4 * 72;
  unsigned short* gZHp  = xqLp + 4 * 72;           // [4][72]
  unsigned short* gZLp  = gZHp + 4 * 72;
  float* Z1L  = (float*)(gZLp + 4 * 72);           // [4][256] Z1 / gZ1 / Z1q
  float* GPf  = Z1L + 1024;                        // [4][256] gelu'
  float* Z2f  = GPf + 1024;                        // [4][64]  gZ2 fp32
  float* redS = Z2f + 256;                         // [2][4][64]
  float* xvL  = redS + 512;                        // [4][64]
  float* b1L  = xvL + 256;                         // [256]
  float* b2L  = b1L + 256;                         // [64]
  float* lwL  = b2L + 64;
  float* lbL  = lwL + 64;

  const int bh = blockIdx.x, b = bh >> 2, h = bh & 3;
  const int t = threadIdx.x;           // 0..511
  const int w8 = t >> 6;               // wave 0..7
  const int lane = t & 63;
  const int a = lane & 15, g = lane >> 4;
  const bool rowv = (a < 4), g0 = (g == 0);
  const int c0 = (2 * w8) * 16 + a;
  const int c1 = (2 * w8 + 1) * 16 + a;
  const int kh = w8 & 1;
  const int jc = (w8 >> 1) * 16 + a;

  FB zf; zf.d[0] = zf.d[1] = zf.d[2] = zf.d[3] = 0;

  // ---- init: W1 fragments in registers ----
  FB w1h[2][2], w1l[2][2];
#pragma unroll
  for (int i = 0; i < 2; ++i) {
    int cc = (2 * w8 + i) * 16 + a;
#pragma unroll
    for (int kc = 0; kc < 2; ++kc) {
#pragma unroll
      for (int e = 0; e < 8; ++e) {
        int k = kc * 32 + g * 8 + e;
        unsigned p = pack_split(W1i[(h * 64 + k) * 256 + cc]);
        w1h[i][kc].u[e] = (unsigned short)(p >> 16);
        w1l[i][kc].u[e] = (unsigned short)(p & 0xFFFFu);
      }
    }
  }
  // W2 planes + W2T planes
  for (int i = 0; i < 32; ++i) {
    int id = t + i * 512;
    int k = id >> 6, j = id & 63;
    unsigned p = pack_split(W2i[(h * 256 + k) * 64 + j]);
    W2Hp[k * 72 + j] = (unsigned short)(p >> 16);
    W2Lp[k * 72 + j] = (unsigned short)(p & 0xFFFFu);
    int j2 = id >> 8, k2 = id & 255;
    unsigned q = pack_split(W2i[(h * 256 + k2) * 64 + j2]);
    W2THp[j2 * 264 + k2] = (unsigned short)(q >> 16);
    W2TLp[j2 * 264 + k2] = (unsigned short)(q & 0xFFFFu);
  }
  if (t < 256) b1L[t] = B1i[h * 256 + t];
  if (t < 64) { b2L[t] = B2i[h * 64 + t]; lwL[t] = LNW[h * 64 + t]; lbL[t] = LNB[h * 64 + t]; }

  const long chain = (long)bh * 65536;
  float rk = 0.f, rv = 0.f, rq = 0.f;
  if (t >= 256) {
    int u = t - 256;
    rk = XK[chain + u]; rv = XV[chain + u]; rq = XQ[chain + u];
  }

  for (int n = 0; n < 256; ++n) {
    // loop top: staging threads commit step-n inputs
    if (t >= 256) {
      int u = t - 256, m = u >> 6, k = u & 63;
      unsigned pk = pack_split(rk), pq = pack_split(rq);
      xkHp[m * 72 + k] = (unsigned short)(pk >> 16);
      xkLp[m * 72 + k] = (unsigned short)(pk & 0xFFFFu);
      xqHp[m * 72 + k] = (unsigned short)(pq >> 16);
      xqLp[m * 72 + k] = (unsigned short)(pq & 0xFFFFu);
      xvL[u] = rv;
    }
    __syncthreads();  // B1

    // ---- S1: Z1 = xk @ W1 + b1 ----
    {
      float bv0 = b1L[c0], bv1 = b1L[c1];
      f32x4 A0 = (f32x4){bv0, bv0, bv0, bv0};
      f32x4 A1 = (f32x4){bv1, bv1, bv1, bv1};
#pragma unroll
      for (int kc = 0; kc < 2; ++kc) {
        int base = kc * 32 + g * 8;
        FB ah = zf, al = zf;
        if (rowv) {
          ah.v = *(const bfrag*)&xkHp[a * 72 + base];
          al.v = *(const bfrag*)&xkLp[a * 72 + base];
        }
        A0 = mm3(ah.v, al.v, w1h[0][kc].v, w1l[0][kc].v, A0);
        A1 = mm3(ah.v, al.v, w1h[1][kc].v, w1l[1][kc].v, A1);
      }
      if (g0) {
#pragma unroll
        for (int q = 0; q < 4; ++q) { Z1L[q * 256 + c0] = A0[q]; Z1L[q * 256 + c1] = A1[q]; }
      }
    }
    __syncthreads();  // B2

    // ---- geluA: X2 = gelu(Z1), GPf = gelu'(Z1) (2 elems/thread) ----
    {
      int idx = t * 2, m = idx >> 8, cc = idx & 255;
      float2 zv = *(const float2*)&Z1L[m * 256 + cc];
      float ex = erff(zv.x * ERF_CF), ey = erff(zv.y * ERF_CF);
      float xx = 0.5f * zv.x * (1.0f + ex), xy = 0.5f * zv.y * (1.0f + ey);
      float gx = 0.5f * (1.0f + ex) + zv.x * expf(-0.5f * zv.x * zv.x) * PDF_CF;
      float gy = 0.5f * (1.0f + ey) + zv.y * expf(-0.5f * zv.y * zv.y) * PDF_CF;
      unsigned px = pack_split(xx), py = pack_split(xy);
      *(unsigned*)&X2Hp[m * 264 + cc] = (px >> 16) | (py & 0xFFFF0000u);
      *(unsigned*)&X2Lp[m * 264 + cc] = (px & 0xFFFFu) | (py << 16);
      *(float2*)&GPf[m * 256 + cc] = make_float2(gx, gy);
    }
    __syncthreads();  // B3

    // ---- S2: Z2 partials (split-K: wave does kh half) ----
    {
      f32x4 acc = (f32x4){0.f, 0.f, 0.f, 0.f};
#pragma unroll
      for (int k4 = 0; k4 < 4; ++k4) {
        int base = (kh * 4 + k4) * 32 + g * 8;
        FB ah = zf, al = zf, bhf, blf;
        if (rowv) {
          ah.v = *(const bfrag*)&X2Hp[a * 264 + base];
          al.v = *(const bfrag*)&X2Lp[a * 264 + base];
        }
        bhf.v = *(const bfrag*)&W2THp[jc * 264 + base];
        blf.v = *(const bfrag*)&W2TLp[jc * 264 + base];
        acc = mm3(ah.v, al.v, bhf.v, blf.v, acc);
      }
      if (g0) {
#pragma unroll
        for (int q = 0; q < 4; ++q) redS[(kh * 4 + q) * 64 + jc] = acc[q];
      }
    }
    __syncthreads();  // B4

    // ---- LN-l2-bwd (waves 0-3) + global prefetch (waves 4-7) ----
    if (t < 256) {
      int m = w8, j = lane;
      float z2 = b2L[j] + redS[m * 64 + j] + redS[256 + m * 64 + j];
      float mu = wsum(z2) * (1.0f / 64.0f);
      float dv = z2 - mu;
      float var = wsum(dv * dv) * (1.0f / 64.0f);
      float stdv = sqrtf(var + 1e-6f);
      float zh = dv / stdv;
      float lw = lwL[j], lb = lbL[j];
      float xkf = uns(xkHp[m * 72 + j], xkLp[m * 72 + j]);
      float tgt = xvL[m * 64 + j] - xkf;
      float gg = lw * (lw * zh + lb - tgt);
      float gs = wsum(gg) * (1.0f / 64.0f);
      float gzs = wsum(gg * zh) * (1.0f / 64.0f);
      float gz2 = (gg - gs - zh * gzs) / stdv;
      unsigned short hsv, lsv;
      split2(gz2, hsv, lsv);
      gZHp[m * 72 + j] = hsv;
      gZLp[m * 72 + j] = lsv;
      Z2f[m * 64 + j] = gz2;
    } else if (n + 1 < 256) {
      int u = t - 256;
      long nb = chain + (long)(n + 1) * 256;
      rk = XK[nb + u]; rv = XV[nb + u]; rq = XQ[nb + u];
    }
    __syncthreads();  // B5

    // ---- S3: gZ1 = (gZ2 @ W2^T) * gelu' ----
    {
      f32x4 A0 = (f32x4){0.f, 0.f, 0.f, 0.f};
      f32x4 A1 = (f32x4){0.f, 0.f, 0.f, 0.f};
#pragma unroll
      for (int kc = 0; kc < 2; ++kc) {
        int base = kc * 32 + g * 8;
        FB ah = zf, al = zf, b0h, b0l, b1h, b1l;
        if (rowv) {
          ah.v = *(const bfrag*)&gZHp[a * 72 + base];
          al.v = *(const bfrag*)&gZLp[a * 72 + base];
        }
        b0h.v = *(const bfrag*)&W2Hp[c0 * 72 + base];
        b0l.v = *(const bfrag*)&W2Lp[c0 * 72 + base];
        b1h.v = *(const bfrag*)&W2Hp[c1 * 72 + base];
        b1l.v = *(const bfrag*)&W2Lp[c1 * 72 + base];
        A0 = mm3(ah.v, al.v, b0h.v, b0l.v, A0);
        A1 = mm3(ah.v, al.v, b1h.v, b1l.v, A1);
      }
      if (g0) {
#pragma unroll
        for (int q = 0; q < 4; ++q) {
          Z1L[q * 256 + c0] = A0[q] * GPf[q * 256 + c0];
          Z1L[q * 256 + c1] = A1[q] * GPf[q * 256 + c1];
        }
      }
    }
    __syncthreads();  // B6

    // ---- UPD ----
    {
      // (a) W1 fragments in registers
      float gzA[4], gzB[4];
#pragma unroll
      for (int m = 0; m < 4; ++m) { gzA[m] = Z1L[m * 256 + c0]; gzB[m] = Z1L[m * 256 + c1]; }
#pragma unroll
      for (int kc = 0; kc < 2; ++kc) {
        int base = kc * 32 + g * 8;
        FB x0h, x0l, x1h, x1l, x2h, x2l, x3h, x3l;
        x0h.v = *(const bfrag*)&xkHp[0 * 72 + base]; x0l.v = *(const bfrag*)&xkLp[0 * 72 + base];
        x1h.v = *(const bfrag*)&xkHp[1 * 72 + base]; x1l.v = *(const bfrag*)&xkLp[1 * 72 + base];
        x2h.v = *(const bfrag*)&xkHp[2 * 72 + base]; x2l.v = *(const bfrag*)&xkLp[2 * 72 + base];
        x3h.v = *(const bfrag*)&xkHp[3 * 72 + base]; x3l.v = *(const bfrag*)&xkLp[3 * 72 + base];
#pragma unroll
        for (int e = 0; e < 8; ++e) {
          float k0 = fb_el(x0h, x0l, e), k1 = fb_el(x1h, x1l, e);
          float k2 = fb_el(x2h, x2l, e), k3 = fb_el(x3h, x3l, e);
          float uA = fmaf(k3, gzA[3], fmaf(k2, gzA[2], fmaf(k1, gzA[1], k0 * gzA[0])));
          float uB = fmaf(k3, gzB[3], fmaf(k2, gzB[2], fmaf(k1, gzB[1], k0 * gzB[0])));
          float fA = fmaf(-ETA, uA, fb_el(w1h[0][kc], w1l[0][kc], e));
          float fB = fmaf(-ETA, uB, fb_el(w1h[1][kc], w1l[1][kc], e));
          unsigned short hs, ls;
          split2(fA, hs, ls); w1h[0][kc].u[e] = hs; w1l[0][kc].u[e] = ls;
          split2(fB, hs, ls); w1h[1][kc].u[e] = hs; w1l[1][kc].u[e] = ls;
        }
      }
      // (b) W2 row (k=t&255, j half = t>>8) + W2T scatter
      {
        int kr = t & 255, j0 = (t >> 8) * 32;
        float x2k0 = uns(X2Hp[0 * 264 + kr], X2Lp[0 * 264 + kr]);
        float x2k1 = uns(X2Hp[1 * 264 + kr], X2Lp[1 * 264 + kr]);
        float x2k2 = uns(X2Hp[2 * 264 + kr], X2Lp[2 * 264 + kr]);
        float x2k3 = uns(X2Hp[3 * 264 + kr], X2Lp[3 * 264 + kr]);
#pragma unroll
        for (int jj = 0; jj < 32; jj += 8) {
          int jb = j0 + jj;
          FB oh, ol, nh, nl;
          oh.v = *(const bfrag*)&W2Hp[kr * 72 + jb];
          ol.v = *(const bfrag*)&W2Lp[kr * 72 + jb];
          float r0[8], r1[8], r2[8], r3[8];
          *(float4*)&r0[0] = *(const float4*)&Z2f[jb];       *(float4*)&r0[4] = *(const float4*)&Z2f[jb + 4];
          *(float4*)&r1[0] = *(const float4*)&Z2f[64 + jb];  *(float4*)&r1[4] = *(const float4*)&Z2f[64 + jb + 4];
          *(float4*)&r2[0] = *(const float4*)&Z2f[128 + jb]; *(float4*)&r2[4] = *(const float4*)&Z2f[128 + jb + 4];
          *(float4*)&r3[0] = *(const float4*)&Z2f[192 + jb]; *(float4*)&r3[4] = *(const float4*)&Z2f[192 + jb + 4];
#pragma unroll
          for (int e = 0; e < 8; ++e) {
            float u = fmaf(x2k3, r3[e], fmaf(x2k2, r2[e], fmaf(x2k1, r1[e], x2k0 * r0[e])));
            float f = fmaf(-ETA, u, fb_el(oh, ol, e));
            unsigned short hs, ls;
            split2(f, hs, ls);
            nh.u[e] = hs; nl.u[e] = ls;
            W2THp[(jb + e) * 264 + kr] = hs;
            W2TLp[(jb + e) * 264 + kr] = ls;
          }
          *(bfrag*)&W2Hp[kr * 72 + jb] = nh.v;
          *(bfrag*)&W2Lp[kr * 72 + jb] = nl.v;
        }
      }
      if (t < 256)
        b1L[t] -= ETA * (((Z1L[t] + Z1L[256 + t]) + Z1L[512 + t]) + Z1L[768 + t]);
      if (t < 64)
        b2L[t] -= ETA * (((Z2f[t] + Z2f[64 + t]) + Z2f[128 + t]) + Z2f[192 + t]);
    }
    __syncthreads();  // B7

    // ---- S6: Z1q = xq @ W1' + b1' ----
    {
      float bv0 = b1L[c0], bv1 = b1L[c1];
      f32x4 A0 = (f32x4){bv0, bv0, bv0, bv0};
      f32x4 A1 = (f32x4){bv1, bv1, bv1, bv1};
#pragma unroll
      for (int kc = 0; kc < 2; ++kc) {
        int base = kc * 32 + g * 8;
        FB ah = zf, al = zf;
        if (rowv) {
          ah.v = *(const bfrag*)&xqHp[a * 72 + base];
          al.v = *(const bfrag*)&xqLp[a * 72 + base];
        }
        A0 = mm3(ah.v, al.v, w1h[0][kc].v, w1l[0][kc].v, A0);
        A1 = mm3(ah.v, al.v, w1h[1][kc].v, w1l[1][kc].v, A1);
      }
      if (g0) {
#pragma unroll
        for (int q = 0; q < 4; ++q) { Z1L[q * 256 + c0] = A0[q]; Z1L[q * 256 + c1] = A1[q]; }
      }
    }
    __syncthreads();  // B8

    // ---- geluB: X2q = gelu(Z1q) ----
    {
      int idx = t * 2, m = idx >> 8, cc = idx & 255;
      float2 zv = *(const float2*)&Z1L[m * 256 + cc];
      float ex = erff(zv.x * ERF_CF), ey = erff(zv.y * ERF_CF);
      unsigned px = pack_split(0.5f * zv.x * (1.0f + ex));
      unsigned py = pack_split(0.5f * zv.y * (1.0f + ey));
      *(unsigned*)&X2Hp[m * 264 + cc] = (px >> 16) | (py & 0xFFFF0000u);
      *(unsigned*)&X2Lp[m * 264 + cc] = (px & 0xFFFFu) | (py << 16);
    }
    __syncthreads();  // B9

    // ---- S7: Z2q partials (updated W2T) ----
    {
      f32x4 acc = (f32x4){0.f, 0.f, 0.f, 0.f};
#pragma unroll
      for (int k4 = 0; k4 < 4; ++k4) {
        int base = (kh * 4 + k4) * 32 + g * 8;
        FB ah = zf, al = zf, bhf, blf;
        if (rowv) {
          ah.v = *(const bfrag*)&X2Hp[a * 264 + base];
          al.v = *(const bfrag*)&X2Lp[a * 264 + base];
        }
        bhf.v = *(const bfrag*)&W2THp[jc * 264 + base];
        blf.v = *(const bfrag*)&W2TLp[jc * 264 + base];
        acc = mm3(ah.v, al.v, bhf.v, blf.v, acc);
      }
      if (g0) {
#pragma unroll
        for (int q = 0; q < 4; ++q) redS[(kh * 4 + q) * 64 + jc] = acc[q];
      }
    }
    __syncthreads();  // B10

    // ---- LN fwd + residual + output (waves 0-3) ----
    if (t < 256) {
      int m = w8, j = lane;
      float z = b2L[j] + redS[m * 64 + j] + redS[256 + m * 64 + j];
      float mu = wsum(z) * (1.0f / 64.0f);
      float dv = z - mu;
      float var = wsum(dv * dv) * (1.0f / 64.0f);
      float rstd = rsqrtf(var + 1e-6f);
      float xqf = uns(xqHp[m * 72 + j], xqLp[m * 72 + j]);
      float val = lwL[j] * dv * rstd + lbL[j] + xqf;
      outp[((long)(b * 1024 + n * 4 + m)) * 256 + h * 64 + j] = val;
    }
    __syncthreads();  // B11
  }
}

// final (4096,64) @ (64,1) + b
__global__ __launch_bounds__(256) void fc3_kernel(const float* __restrict__ f2,
                                                  const float* __restrict__ w,
                                                  const float* __restrict__ bias,
                                                  float* __restrict__ o) {
  int m = blockIdx.x * 4 + (threadIdx.x >> 6);
  int lane = threadIdx.x & 63;
  float v = f2[m * 64 + lane] * w[lane];
  v = wsum(v);
  if (lane == 0) o[m] = v + bias[0];
}

// ---------------------------------------------------------------------------
extern "C" void kernel_launch(void* const* d_in, const int* in_sizes, int n_in,
                              void* d_out, int out_size, void* d_ws, size_t ws_size,
                              hipStream_t stream) {
  const float* x       = (const float*)d_in[0];
  const float* conv1_w = (const float*)d_in[1];
  const float* conv1_b = (const float*)d_in[2];
  const float* convs_w = (const float*)d_in[3];
  const float* convs_b = (const float*)d_in[4];
  const float* ln_w    = (const float*)d_in[5];
  const float* ln_b    = (const float*)d_in[6];
  const float* wq      = (const float*)d_in[7];
  const float* wk      = (const float*)d_in[8];
  const float* wv      = (const float*)d_in[9];
  const float* wo      = (const float*)d_in[10];
  const float* ttt_W1  = (const float*)d_in[11];
  const float* ttt_b1  = (const float*)d_in[12];
  const float* ttt_W2  = (const float*)d_in[13];
  const float* ttt_b2  = (const float*)d_in[14];
  const float* ttt_lnw = (const float*)d_in[15];
  const float* ttt_lnb = (const float*)d_in[16];
  const float* fc_w    = (const float*)d_in[17];
  const float* fc_b    = (const float*)d_in[18];
  const float* fc2_w   = (const float*)d_in[19];
  const float* fc2_b   = (const float*)d_in[20];
  const float* fc3_w   = (const float*)d_in[21];
  const float* fc3_b   = (const float*)d_in[22];

  float* ws = (float*)d_ws;
  float* wt1  = ws + 0;
  float* wt   = ws + 16384;
  float* bufA = ws + 1589248;
  float* bufB = ws + 2639872;
  float* sum4 = ws + 3690496;
  float* tln  = ws + 4739072;
  float* XQ   = ws + 5787648;
  float* XK   = ws + 6836224;
  float* XV   = ws + 7884800;
  float* tout = ws + 8933376;
  float* tfull = sum4;
  float* h2    = bufA;
  float* f1    = XQ;
  float* f2    = tout;

  const int M = 4096;
  dim3 blk(256);

  zero_halo<<<16, blk, 0, stream>>>(bufA, bufB);
  prep_w<<<6208, blk, 0, stream>>>(conv1_w, convs_w, wt1, wt);

  gemm_k<1, 1, 0, 1, 0><<<dim3(64, 4), blk, 0, stream>>>(
      x, wt1, conv1_b, nullptr, bufA, nullptr, M, 256, 64, 64, 0);

  for (int i = 0; i < 8; ++i) {
    const float* in = (i % 2 == 0) ? bufA : bufB;
    float* out = (i % 2 == 0) ? bufB : bufA;
    const float* wp = wt + (size_t)i * 196608;
    const float* bp = convs_b + i * 256;
    if (i == 1)
      gemm_k<1, 1, 0, 1, 1><<<dim3(64, 4), blk, 0, stream>>>(
          in, wp, bp, nullptr, out, sum4, M, 256, 768, 256, 1);
    else if (i == 3 || i == 5 || i == 7)
      gemm_k<1, 1, 0, 1, 2><<<dim3(64, 4), blk, 0, stream>>>(
          in, wp, bp, nullptr, out, sum4, M, 256, 768, 256, 1);
    else
      gemm_k<1, 1, 0, 1, 0><<<dim3(64, 4), blk, 0, stream>>>(
          in, wp, bp, nullptr, out, sum4, M, 256, 768, 256, 1);
  }

  ln_kernel<<<1024, blk, 0, stream>>>(sum4, tln, ln_w, ln_b, 1e-5f);

  gemm_k<0, 0, 0, 2, 0><<<dim3(64, 4), blk, 0, stream>>>(
      tln, wq, nullptr, nullptr, XQ, nullptr, M, 256, 256, 256, 0);
  gemm_k<0, 0, 0, 2, 0><<<dim3(64, 4), blk, 0, stream>>>(
      tln, wk, nullptr, nullptr, XK, nullptr, M, 256, 256, 256, 0);
  gemm_k<0, 0, 0, 2, 0><<<dim3(64, 4), blk, 0, stream>>>(
      tln, wv, nullptr, nullptr, XV, nullptr, M, 256, 256, 256, 0);

  // TTT scan (MFMA): 16 chains, 512 threads, 163072 B dynamic LDS
  const int TTT_LDS = 163072;
  (void)hipFuncSetAttribute((const void*)ttt_mfma,
                            hipFuncAttributeMaxDynamicSharedMemorySize, TTT_LDS);
  ttt_mfma<<<16, dim3(512), TTT_LDS, stream>>>(XQ, XK, XV, ttt_W1, ttt_b1,
                                               ttt_W2, ttt_b2, ttt_lnw, ttt_lnb,
                                               tout);

  gemm_k<0, 0, 1, 0, 0><<<dim3(64, 4), blk, 0, stream>>>(
      tout, wo, nullptr, tln, tfull, nullptr, M, 256, 256, 256, 0);

  ln_kernel<<<1024, blk, 0, stream>>>(tfull, h2, ln_w, ln_b, 1e-5f);

  gemm_k<1, 0, 0, 0, 0><<<dim3(64, 8), blk, 0, stream>>>(
      h2, fc_w, fc_b, nullptr, f1, nullptr, M, 512, 256, 256, 0);
  gemm_k<1, 0, 0, 0, 0><<<dim3(64, 1), blk, 0, stream>>>(
      f1, fc2_w, fc2_b, nullptr, f2, nullptr, M, 64, 512, 512, 0);
  fc3_kernel<<<1024, blk, 0, stream>>>(f2, fc3_w, fc3_b, (float*)d_out);
}

// Round 7
// 3056.137 us; speedup vs baseline: 3.1519x; 1.2371x over previous
//
#include <hip/hip_runtime.h>
#include <hip/hip_bf16.h>

// ResNetTTT. Round 7: TTT MFMA kernel, 8-barrier step:
//  - gelu fused into MFMA accumulator lanes (gelu' stays in registers)
//  - b1 in registers (no barrier between W1 update and S6)
//  - W2T update row-major vectorized (b128 RMW), bit-identical to W2 copy
//  - fp32 X2F sidecar for weight updates; padded strides (80/272/264/72)

#define ERF_CF 0.70710678118654752f
#define PDF_CF 0.3989422804014327f
#define ETA 0.025f   // TTT_LR / MB

typedef __attribute__((ext_vector_type(8))) short bfrag;    // 8 bf16 (4 VGPR)
typedef __attribute__((ext_vector_type(4))) float f32x4;

union FB { bfrag v; unsigned short u[8]; unsigned d[4]; };

__device__ __forceinline__ float wsum(float v) {
#pragma unroll
  for (int o = 32; o > 0; o >>= 1) v += __shfl_xor(v, o, 64);
  return v;
}

__device__ __forceinline__ unsigned pack_split(float x) {
  unsigned u = __float_as_uint(x);
  unsigned hb = u & 0xFFFF0000u;
  float lf = x - __uint_as_float(hb);
  return hb | (__float_as_uint(lf) >> 16);
}
__device__ __forceinline__ float uns(unsigned short hs, unsigned short ls) {
  return __uint_as_float((unsigned)hs << 16) + __uint_as_float((unsigned)ls << 16);
}
__device__ __forceinline__ float fb_el(const FB& H, const FB& L, int e) {
  return __uint_as_float((unsigned)H.u[e] << 16) +
         __uint_as_float((unsigned)L.u[e] << 16);
}
__device__ __forceinline__ void split2(float f, unsigned short& hs, unsigned short& ls) {
  unsigned u = __float_as_uint(f);
  unsigned hb = u & 0xFFFF0000u;
  hs = (unsigned short)(u >> 16);
  ls = (unsigned short)(__float_as_uint(f - __uint_as_float(hb)) >> 16);
}
__device__ __forceinline__ f32x4 mm3(bfrag ah, bfrag al, bfrag bh, bfrag bl, f32x4 acc) {
  acc = __builtin_amdgcn_mfma_f32_16x16x32_bf16(ah, bh, acc, 0, 0, 0);
  acc = __builtin_amdgcn_mfma_f32_16x16x32_bf16(ah, bl, acc, 0, 0, 0);
  acc = __builtin_amdgcn_mfma_f32_16x16x32_bf16(al, bh, acc, 0, 0, 0);
  return acc;
}

// ---------------------------------------------------------------------------
__global__ void prep_w(const float* __restrict__ c1w, const float* __restrict__ cw,
                       float* __restrict__ wt1, float* __restrict__ wt) {
  int id = blockIdx.x * 256 + threadIdx.x;
  if (id < 16384) {
    int ci = id >> 8, co = id & 255;
    wt1[id] = c1w[co * 64 + ci];
  }
  int id2 = id - 16384;
  if (id2 >= 0 && id2 < 1572864) {
    int cv = id2 / 196608;
    int r = id2 - cv * 196608;
    int k = r >> 8, co = r & 255;
    int tt = k >> 8, ci = k & 255;
    wt[id2] = cw[((cv * 256 + co) * 256 + ci) * 3 + tt];
  }
}

__global__ void zero_halo(float* __restrict__ bufA, float* __restrict__ bufB) {
  int id = blockIdx.x * 256 + threadIdx.x;
  int c = id & 255;
  int row = (id >> 8) & 1;
  int b = (id >> 9) & 3;
  float* p = (id >> 11) ? bufB : bufA;
  p[(b * 1026 + row * 1025) * 256 + c] = 0.0f;
}

template <int BIAS, int RELU, int RES, int OST, int ACC>
__global__ __launch_bounds__(256) void gemm_k(
    const float* __restrict__ A, const float* __restrict__ Wt,
    const float* __restrict__ bias, const float* __restrict__ res,
    float* __restrict__ out, float* __restrict__ accp,
    int M, int N, int K, int lda, int haloA) {
  __shared__ float As[16][68];
  __shared__ float Bs[16][64];
  const int tid = threadIdx.x;
  const int bm = blockIdx.x * 64, bn = blockIdx.y * 64;
  const int tx = tid & 15, ty = tid >> 4;
  float acc[4][4] = {};

  for (int k0 = 0; k0 < K; k0 += 16) {
#pragma unroll
    for (int i = 0; i < 4; ++i) {
      int idx = tid + i * 256;
      int kk = idx & 15, mm = idx >> 4;
      int m = bm + mm;
      int rb = m * lda + (haloA ? ((m >> 10) << 9) : 0);
      As[kk][mm] = A[rb + k0 + kk];
    }
#pragma unroll
    for (int i = 0; i < 4; ++i) {
      int idx = tid + i * 256;
      int nn = idx & 63, kk = idx >> 6;
      Bs[kk][nn] = Wt[(k0 + kk) * N + bn + nn];
    }
    __syncthreads();
#pragma unroll
    for (int kk = 0; kk < 16; ++kk) {
      float4 av = *(const float4*)&As[kk][ty * 4];
      float4 bv = *(const float4*)&Bs[kk][tx * 4];
      float aa[4] = {av.x, av.y, av.z, av.w};
      float bb[4] = {bv.x, bv.y, bv.z, bv.w};
#pragma unroll
      for (int i = 0; i < 4; ++i)
#pragma unroll
        for (int j = 0; j < 4; ++j) acc[i][j] = fmaf(aa[i], bb[j], acc[i][j]);
    }
    __syncthreads();
  }

  const int n0 = bn + tx * 4;
#pragma unroll
  for (int i = 0; i < 4; ++i) {
    int m = bm + ty * 4 + i;
    int b_ = m >> 10, l = m & 1023;
    float v[4];
#pragma unroll
    for (int j = 0; j < 4; ++j) {
      float x = acc[i][j];
      if constexpr (BIAS) x += bias[n0 + j];
      if constexpr (RELU) x = fmaxf(x, 0.0f);
      if constexpr (RES) x += res[m * N + n0 + j];
      v[j] = x;
    }
    float4 vv = make_float4(v[0], v[1], v[2], v[3]);
    if constexpr (OST == 0) {
      *(float4*)&out[m * N + n0] = vv;
    } else if constexpr (OST == 1) {
      *(float4*)&out[(b_ * 1026 + l + 1) * 256 + n0] = vv;
    } else {
      int hq = n0 >> 6;
      int oidx = (((b_ * 4 + hq) * 1024 + l) << 6) + (n0 & 63);
      *(float4*)&out[oidx] = vv;
    }
    if constexpr (ACC == 1) {
      *(float4*)&accp[m * 256 + n0] = vv;
    } else if constexpr (ACC == 2) {
      float4 s = *(const float4*)&accp[m * 256 + n0];
      s.x += vv.x; s.y += vv.y; s.z += vv.z; s.w += vv.w;
      *(float4*)&accp[m * 256 + n0] = s;
    }
  }
}

__global__ __launch_bounds__(256) void ln_kernel(const float* __restrict__ in,
                                                 float* __restrict__ o,
                                                 const float* __restrict__ w,
                                                 const float* __restrict__ bb,
                                                 float eps) {
  int row = blockIdx.x * 4 + (threadIdx.x >> 6);
  int l = threadIdx.x & 63;
  float4 v = ((const float4*)(in + (long)row * 256))[l];
  float s = wsum(v.x + v.y + v.z + v.w);
  float mu = s * (1.0f / 256.0f);
  float dx = v.x - mu, dy = v.y - mu, dz = v.z - mu, dw = v.w - mu;
  float rstd = rsqrtf(wsum(dx * dx + dy * dy + dz * dz + dw * dw) * (1.0f / 256.0f) + eps);
  float4 wv = ((const float4*)w)[l];
  float4 bv = ((const float4*)bb)[l];
  float4 r;
  r.x = wv.x * dx * rstd + bv.x;
  r.y = wv.y * dy * rstd + bv.y;
  r.z = wv.z * dz * rstd + bv.z;
  r.w = wv.w * dw * rstd + bv.w;
  ((float4*)(o + (long)row * 256))[l] = r;
}

// ---------------------------------------------------------------------------
// TTT scan via MFMA, 512 threads (8 waves) per (b,h) chain. 8 barriers/step.
// ---------------------------------------------------------------------------
__global__ __launch_bounds__(512, 2) void ttt_mfma(
    const float* __restrict__ XQ, const float* __restrict__ XK,
    const float* __restrict__ XV, const float* __restrict__ W1i,
    const float* __restrict__ B1i, const float* __restrict__ W2i,
    const float* __restrict__ B2i, const float* __restrict__ LNW,
    const float* __restrict__ LNB, float* __restrict__ outp) {
  extern __shared__ char smem[];
  unsigned short* W2Hp  = (unsigned short*)smem;   // [256][72]
  unsigned short* W2Lp  = W2Hp + 256 * 72;
  unsigned short* W2THp = W2Lp + 256 * 72;         // [64][264]
  unsigned short* W2TLp = W2THp + 64 * 264;
  unsigned short* X2Hp  = W2TLp + 64 * 264;        // [4][272]
  unsigned short* X2Lp  = X2Hp + 4 * 272;
  unsigned short* xkHp  = X2Lp + 4 * 272;          // [4][80]
  unsigned short* xkLp  = xkHp + 4 * 80;
  unsigned short* xqHp  = xkLp + 4 * 80;
  unsigned short* xqLp  = xqHp + 4 * 80;
  unsigned short* gZHp  = xqLp + 4 * 80;           // [4][80]
  unsigned short* gZLp  = gZHp + 4 * 80;
  float* X2F  = (float*)(gZLp + 4 * 80);           // [4][264] fp32 X2
  float* gZ1f = X2F + 4 * 264;                     // [4][256]
  float* Z2f  = gZ1f + 1024;                       // [4][64] gZ2 fp32
  float* redS = Z2f + 256;                         // [2][4][64]
  float* xvL  = redS + 512;                        // [4][64]
  float* b2L  = xvL + 256;                         // [64]
  float* lwL  = b2L + 64;
  float* lbL  = lwL + 64;

  const int bh = blockIdx.x, b = bh >> 2, h = bh & 3;
  const int t = threadIdx.x;           // 0..511
  const int w8 = t >> 6;
  const int lane = t & 63;
  const int a = lane & 15, g = lane >> 4;
  const bool rowv = (a < 4), g0 = (g == 0);
  const int c0 = 32 * w8 + a;
  const int c1 = 32 * w8 + 16 + a;
  const int kh = w8 & 1;
  const int jc = (w8 >> 1) * 16 + a;

  FB zf; zf.d[0] = zf.d[1] = zf.d[2] = zf.d[3] = 0;

  // ---- init W1 fragments (registers) + b1 regs ----
  FB w1h[2][2], w1l[2][2];
#pragma unroll
  for (int i = 0; i < 2; ++i) {
    int cc = 32 * w8 + i * 16 + a;
#pragma unroll
    for (int kc = 0; kc < 2; ++kc) {
#pragma unroll
      for (int e = 0; e < 8; ++e) {
        int k = kc * 32 + g * 8 + e;
        unsigned p = pack_split(W1i[(h * 64 + k) * 256 + cc]);
        w1h[i][kc].u[e] = (unsigned short)(p >> 16);
        w1l[i][kc].u[e] = (unsigned short)(p & 0xFFFFu);
      }
    }
  }
  float b1r0 = B1i[h * 256 + c0];
  float b1r1 = B1i[h * 256 + c1];

  // W2 + W2T planes
  for (int i = 0; i < 32; ++i) {
    int id = t + i * 512;
    int k = id >> 6, j = id & 63;
    unsigned p = pack_split(W2i[(h * 256 + k) * 64 + j]);
    W2Hp[k * 72 + j] = (unsigned short)(p >> 16);
    W2Lp[k * 72 + j] = (unsigned short)(p & 0xFFFFu);
    int j2 = id >> 8, k2 = id & 255;
    unsigned q = pack_split(W2i[(h * 256 + k2) * 64 + j2]);
    W2THp[j2 * 264 + k2] = (unsigned short)(q >> 16);
    W2TLp[j2 * 264 + k2] = (unsigned short)(q & 0xFFFFu);
  }
  if (t < 64) { b2L[t] = B2i[h * 64 + t]; lwL[t] = LNW[h * 64 + t]; lbL[t] = LNB[h * 64 + t]; }

  const long chain = (long)bh * 65536;
  float rk = 0.f, rv = 0.f, rq = 0.f;
  if (t >= 256) {
    int u = t - 256;
    rk = XK[chain + u]; rv = XV[chain + u]; rq = XQ[chain + u];
  }

  for (int n = 0; n < 256; ++n) {
    // ---- stage inputs (waves 4-7) ----
    if (t >= 256) {
      int u = t - 256, m = u >> 6, k = u & 63;
      unsigned short hs, ls;
      split2(rk, hs, ls); xkHp[m * 80 + k] = hs; xkLp[m * 80 + k] = ls;
      split2(rq, hs, ls); xqHp[m * 80 + k] = hs; xqLp[m * 80 + k] = ls;
      xvL[u] = rv;
    }
    __syncthreads();  // B1

    float gpA[4] = {0.f, 0.f, 0.f, 0.f}, gpB[4] = {0.f, 0.f, 0.f, 0.f};

    // ---- S1: Z1 = xk @ W1 + b1 ; in-reg gelu -> X2 planes + X2F ----
    {
      f32x4 A0 = (f32x4){b1r0, b1r0, b1r0, b1r0};
      f32x4 A1 = (f32x4){b1r1, b1r1, b1r1, b1r1};
#pragma unroll
      for (int kc = 0; kc < 2; ++kc) {
        int base = kc * 32 + g * 8;
        FB ah = zf, al = zf;
        if (rowv) {
          ah.v = *(const bfrag*)&xkHp[a * 80 + base];
          al.v = *(const bfrag*)&xkLp[a * 80 + base];
        }
        A0 = mm3(ah.v, al.v, w1h[0][kc].v, w1l[0][kc].v, A0);
        A1 = mm3(ah.v, al.v, w1h[1][kc].v, w1l[1][kc].v, A1);
      }
      if (g0) {
#pragma unroll
        for (int q = 0; q < 4; ++q) {
          float z = A0[q];
          float er = erff(z * ERF_CF);
          float hh = 0.5f * (1.0f + er);
          float x2 = z * hh;
          gpA[q] = hh + z * __expf(-0.5f * z * z) * PDF_CF;
          unsigned short hs, ls;
          split2(x2, hs, ls);
          X2Hp[q * 272 + c0] = hs; X2Lp[q * 272 + c0] = ls;
          X2F[q * 264 + c0] = x2;
          z = A1[q];
          er = erff(z * ERF_CF);
          hh = 0.5f * (1.0f + er);
          x2 = z * hh;
          gpB[q] = hh + z * __expf(-0.5f * z * z) * PDF_CF;
          split2(x2, hs, ls);
          X2Hp[q * 272 + c1] = hs; X2Lp[q * 272 + c1] = ls;
          X2F[q * 264 + c1] = x2;
        }
      }
    }
    __syncthreads();  // B2

    // ---- S2: Z2 partials (split-K over kh) ----
    {
      f32x4 acc = (f32x4){0.f, 0.f, 0.f, 0.f};
#pragma unroll
      for (int k4 = 0; k4 < 4; ++k4) {
        int base = (kh * 4 + k4) * 32 + g * 8;
        FB ah = zf, al = zf, bhf, blf;
        if (rowv) {
          ah.v = *(const bfrag*)&X2Hp[a * 272 + base];
          al.v = *(const bfrag*)&X2Lp[a * 272 + base];
        }
        bhf.v = *(const bfrag*)&W2THp[jc * 264 + base];
        blf.v = *(const bfrag*)&W2TLp[jc * 264 + base];
        acc = mm3(ah.v, al.v, bhf.v, blf.v, acc);
      }
      if (g0) {
#pragma unroll
        for (int q = 0; q < 4; ++q) redS[(kh * 4 + q) * 64 + jc] = acc[q];
      }
    }
    __syncthreads();  // B3

    // ---- LN-l2-bwd (waves 0-3) + prefetch (waves 4-7) ----
    if (t < 256) {
      int m = w8, j = lane;
      float z2 = b2L[j] + redS[m * 64 + j] + redS[256 + m * 64 + j];
      float mu = wsum(z2) * (1.0f / 64.0f);
      float dv = z2 - mu;
      float var = wsum(dv * dv) * (1.0f / 64.0f);
      float stdv = sqrtf(var + 1e-6f);
      float zh = dv / stdv;
      float lw = lwL[j], lb = lbL[j];
      float xkf = uns(xkHp[m * 80 + j], xkLp[m * 80 + j]);
      float tgt = xvL[m * 64 + j] - xkf;
      float gg = lw * (lw * zh + lb - tgt);
      float gs = wsum(gg) * (1.0f / 64.0f);
      float gzs = wsum(gg * zh) * (1.0f / 64.0f);
      float gz2 = (gg - gs - zh * gzs) / stdv;
      unsigned short hs, ls;
      split2(gz2, hs, ls);
      gZHp[m * 80 + j] = hs; gZLp[m * 80 + j] = ls;
      Z2f[m * 64 + j] = gz2;
    } else if (n + 1 < 256) {
      int u = t - 256;
      long nb = chain + (long)(n + 1) * 256;
      rk = XK[nb + u]; rv = XV[nb + u]; rq = XQ[nb + u];
    }
    __syncthreads();  // B4

    // ---- S3 (gZ1) overlapped with W2T RMW ----
    {
      f32x4 A0 = (f32x4){0.f, 0.f, 0.f, 0.f};
      f32x4 A1 = (f32x4){0.f, 0.f, 0.f, 0.f};
#pragma unroll
      for (int kc = 0; kc < 2; ++kc) {
        int base = kc * 32 + g * 8;
        FB ah = zf, al = zf, b0h, b0l, b1h, b1l;
        if (rowv) {
          ah.v = *(const bfrag*)&gZHp[a * 80 + base];
          al.v = *(const bfrag*)&gZLp[a * 80 + base];
        }
        b0h.v = *(const bfrag*)&W2Hp[c0 * 72 + base];
        b0l.v = *(const bfrag*)&W2Lp[c0 * 72 + base];
        b1h.v = *(const bfrag*)&W2Hp[c1 * 72 + base];
        b1l.v = *(const bfrag*)&W2Lp[c1 * 72 + base];
        A0 = mm3(ah.v, al.v, b0h.v, b0l.v, A0);
        A1 = mm3(ah.v, al.v, b1h.v, b1l.v, A1);
      }
      if (g0) {
#pragma unroll
        for (int q = 0; q < 4; ++q) {
          gZ1f[q * 256 + c0] = A0[q] * gpA[q];
          gZ1f[q * 256 + c1] = A1[q] * gpB[q];
        }
      }
      // W2T RMW (row jr, 32 k's) — bit-identical chain to W2 RMW below
      {
        int jr = t & 63, kb = (t >> 6) * 32;
        float gz0 = Z2f[jr], gz1 = Z2f[64 + jr], gz2 = Z2f[128 + jr], gz3 = Z2f[192 + jr];
#pragma unroll
        for (int kk = 0; kk < 32; kk += 8) {
          int kb8 = kb + kk;
          float x0[8], x1[8], x2[8], x3[8];
          *(float4*)&x0[0] = *(const float4*)&X2F[kb8];        *(float4*)&x0[4] = *(const float4*)&X2F[kb8 + 4];
          *(float4*)&x1[0] = *(const float4*)&X2F[264 + kb8];  *(float4*)&x1[4] = *(const float4*)&X2F[264 + kb8 + 4];
          *(float4*)&x2[0] = *(const float4*)&X2F[528 + kb8];  *(float4*)&x2[4] = *(const float4*)&X2F[528 + kb8 + 4];
          *(float4*)&x3[0] = *(const float4*)&X2F[792 + kb8];  *(float4*)&x3[4] = *(const float4*)&X2F[792 + kb8 + 4];
          FB oh, ol, nh, nl;
          oh.v = *(const bfrag*)&W2THp[jr * 264 + kb8];
          ol.v = *(const bfrag*)&W2TLp[jr * 264 + kb8];
#pragma unroll
          for (int e = 0; e < 8; ++e) {
            float u = fmaf(x3[e], gz3, fmaf(x2[e], gz2, fmaf(x1[e], gz1, x0[e] * gz0)));
            float f = fmaf(-ETA, u, fb_el(oh, ol, e));
            unsigned short hs, ls;
            split2(f, hs, ls);
            nh.u[e] = hs; nl.u[e] = ls;
          }
          *(bfrag*)&W2THp[jr * 264 + kb8] = nh.v;
          *(bfrag*)&W2TLp[jr * 264 + kb8] = nl.v;
        }
      }
    }
    __syncthreads();  // B5

    // ---- W1/b1 reg update ; S6 ; gelu ; W2 RMW ; b2 ----
    {
      float gzA0 = gZ1f[c0], gzA1 = gZ1f[256 + c0], gzA2 = gZ1f[512 + c0], gzA3 = gZ1f[768 + c0];
      float gzB0 = gZ1f[c1], gzB1 = gZ1f[256 + c1], gzB2 = gZ1f[512 + c1], gzB3 = gZ1f[768 + c1];
      b1r0 = fmaf(-ETA, ((gzA0 + gzA1) + gzA2) + gzA3, b1r0);
      b1r1 = fmaf(-ETA, ((gzB0 + gzB1) + gzB2) + gzB3, b1r1);
#pragma unroll
      for (int kc = 0; kc < 2; ++kc) {
        int base = kc * 32 + g * 8;
        FB x0h, x0l, x1h, x1l, x2h, x2l, x3h, x3l;
        x0h.v = *(const bfrag*)&xkHp[base];       x0l.v = *(const bfrag*)&xkLp[base];
        x1h.v = *(const bfrag*)&xkHp[80 + base];  x1l.v = *(const bfrag*)&xkLp[80 + base];
        x2h.v = *(const bfrag*)&xkHp[160 + base]; x2l.v = *(const bfrag*)&xkLp[160 + base];
        x3h.v = *(const bfrag*)&xkHp[240 + base]; x3l.v = *(const bfrag*)&xkLp[240 + base];
#pragma unroll
        for (int e = 0; e < 8; ++e) {
          float k0 = fb_el(x0h, x0l, e), k1 = fb_el(x1h, x1l, e);
          float k2 = fb_el(x2h, x2l, e), k3 = fb_el(x3h, x3l, e);
          float uA = fmaf(k3, gzA3, fmaf(k2, gzA2, fmaf(k1, gzA1, k0 * gzA0)));
          float uB = fmaf(k3, gzB3, fmaf(k2, gzB2, fmaf(k1, gzB1, k0 * gzB0)));
          float fA = fmaf(-ETA, uA, fb_el(w1h[0][kc], w1l[0][kc], e));
          float fB = fmaf(-ETA, uB, fb_el(w1h[1][kc], w1l[1][kc], e));
          unsigned short hs, ls;
          split2(fA, hs, ls); w1h[0][kc].u[e] = hs; w1l[0][kc].u[e] = ls;
          split2(fB, hs, ls); w1h[1][kc].u[e] = hs; w1l[1][kc].u[e] = ls;
        }
      }
      // S6: Z1q = xq @ W1' + b1' ; in-reg gelu -> X2 planes
      {
        f32x4 A0 = (f32x4){b1r0, b1r0, b1r0, b1r0};
        f32x4 A1 = (f32x4){b1r1, b1r1, b1r1, b1r1};
#pragma unroll
        for (int kc = 0; kc < 2; ++kc) {
          int base = kc * 32 + g * 8;
          FB ah = zf, al = zf;
          if (rowv) {
            ah.v = *(const bfrag*)&xqHp[a * 80 + base];
            al.v = *(const bfrag*)&xqLp[a * 80 + base];
          }
          A0 = mm3(ah.v, al.v, w1h[0][kc].v, w1l[0][kc].v, A0);
          A1 = mm3(ah.v, al.v, w1h[1][kc].v, w1l[1][kc].v, A1);
        }
        if (g0) {
#pragma unroll
          for (int q = 0; q < 4; ++q) {
            float z = A0[q];
            float x2 = 0.5f * z * (1.0f + erff(z * ERF_CF));
            unsigned short hs, ls;
            split2(x2, hs, ls);
            X2Hp[q * 272 + c0] = hs; X2Lp[q * 272 + c0] = ls;
            z = A1[q];
            x2 = 0.5f * z * (1.0f + erff(z * ERF_CF));
            split2(x2, hs, ls);
            X2Hp[q * 272 + c1] = hs; X2Lp[q * 272 + c1] = ls;
          }
        }
      }
      // W2 RMW (row kr, 32 j's)
      {
        int kr = t & 255, jh = (t >> 8) * 32;
        float xk0 = X2F[kr], xk1 = X2F[264 + kr], xk2 = X2F[528 + kr], xk3 = X2F[792 + kr];
#pragma unroll
        for (int jj = 0; jj < 32; jj += 8) {
          int jb = jh + jj;
          float g0f[8], g1f[8], g2f[8], g3f[8];
          *(float4*)&g0f[0] = *(const float4*)&Z2f[jb];        *(float4*)&g0f[4] = *(const float4*)&Z2f[jb + 4];
          *(float4*)&g1f[0] = *(const float4*)&Z2f[64 + jb];   *(float4*)&g1f[4] = *(const float4*)&Z2f[64 + jb + 4];
          *(float4*)&g2f[0] = *(const float4*)&Z2f[128 + jb];  *(float4*)&g2f[4] = *(const float4*)&Z2f[128 + jb + 4];
          *(float4*)&g3f[0] = *(const float4*)&Z2f[192 + jb];  *(float4*)&g3f[4] = *(const float4*)&Z2f[192 + jb + 4];
          FB oh, ol, nh, nl;
          oh.v = *(const bfrag*)&W2Hp[kr * 72 + jb];
          ol.v = *(const bfrag*)&W2Lp[kr * 72 + jb];
#pragma unroll
          for (int e = 0; e < 8; ++e) {
            float u = fmaf(xk3, g3f[e], fmaf(xk2, g2f[e], fmaf(xk1, g1f[e], xk0 * g0f[e])));
            float f = fmaf(-ETA, u, fb_el(oh, ol, e));
            unsigned short hs, ls;
            split2(f, hs, ls);
            nh.u[e] = hs; nl.u[e] = ls;
          }
          *(bfrag*)&W2Hp[kr * 72 + jb] = nh.v;
          *(bfrag*)&W2Lp[kr * 72 + jb] = nl.v;
        }
      }
      if (t < 64)
        b2L[t] -= ETA * (((Z2f[t] + Z2f[64 + t]) + Z2f[128 + t]) + Z2f[192 + t]);
    }
    __syncthreads();  // B6

    // ---- S7: Z2q partials (updated W2T) ----
    {
      f32x4 acc = (f32x4){0.f, 0.f, 0.f, 0.f};
#pragma unroll
      for (int k4 = 0; k4 < 4; ++k4) {
        int base = (kh * 4 + k4) * 32 + g * 8;
        FB ah = zf, al = zf, bhf, blf;
        if (rowv) {
          ah.v = *(const bfrag*)&X2Hp[a * 272 + base];
          al.v = *(const bfrag*)&X2Lp[a * 272 + base];
        }
        bhf.v = *(const bfrag*)&W2THp[jc * 264 + base];
        blf.v = *(const bfrag*)&W2TLp[jc * 264 + base];
        acc = mm3(ah.v, al.v, bhf.v, blf.v, acc);
      }
      if (g0) {
#pragma unroll
        for (int q = 0; q < 4; ++q) redS[(kh * 4 + q) * 64 + jc] = acc[q];
      }
    }
    __syncthreads();  // B7

    // ---- LN fwd + residual + output (waves 0-3) ----
    if (t < 256) {
      int m = w8, j = lane;
      float z = b2L[j] + redS[m * 64 + j] + redS[256 + m * 64 + j];
      float mu = wsum(z) * (1.0f / 64.0f);
      float dv = z - mu;
      float var = wsum(dv * dv) * (1.0f / 64.0f);
      float rstd = rsqrtf(var + 1e-6f);
      float xqf = uns(xqHp[m * 80 + j], xqLp[m * 80 + j]);
      float val = lwL[j] * dv * rstd + lbL[j] + xqf;
      outp[((long)(b * 1024 + n * 4 + m)) * 256 + h * 64 + j] = val;
    }
    __syncthreads();  // B8
  }
}

// final (4096,64) @ (64,1) + b
__global__ __launch_bounds__(256) void fc3_kernel(const float* __restrict__ f2,
                                                  const float* __restrict__ w,
                                                  const float* __restrict__ bias,
                                                  float* __restrict__ o) {
  int m = blockIdx.x * 4 + (threadIdx.x >> 6);
  int lane = threadIdx.x & 63;
  float v = f2[m * 64 + lane] * w[lane];
  v = wsum(v);
  if (lane == 0) o[m] = v + bias[0];
}

// ---------------------------------------------------------------------------
extern "C" void kernel_launch(void* const* d_in, const int* in_sizes, int n_in,
                              void* d_out, int out_size, void* d_ws, size_t ws_size,
                              hipStream_t stream) {
  const float* x       = (const float*)d_in[0];
  const float* conv1_w = (const float*)d_in[1];
  const float* conv1_b = (const float*)d_in[2];
  const float* convs_w = (const float*)d_in[3];
  const float* convs_b = (const float*)d_in[4];
  const float* ln_w    = (const float*)d_in[5];
  const float* ln_b    = (const float*)d_in[6];
  const float* wq      = (const float*)d_in[7];
  const float* wk      = (const float*)d_in[8];
  const float* wv      = (const float*)d_in[9];
  const float* wo      = (const float*)d_in[10];
  const float* ttt_W1  = (const float*)d_in[11];
  const float* ttt_b1  = (const float*)d_in[12];
  const float* ttt_W2  = (const float*)d_in[13];
  const float* ttt_b2  = (const float*)d_in[14];
  const float* ttt_lnw = (const float*)d_in[15];
  const float* ttt_lnb = (const float*)d_in[16];
  const float* fc_w    = (const float*)d_in[17];
  const float* fc_b    = (const float*)d_in[18];
  const float* fc2_w   = (const float*)d_in[19];
  const float* fc2_b   = (const float*)d_in[20];
  const float* fc3_w   = (const float*)d_in[21];
  const float* fc3_b   = (const float*)d_in[22];

  float* ws = (float*)d_ws;
  float* wt1  = ws + 0;
  float* wt   = ws + 16384;
  float* bufA = ws + 1589248;
  float* bufB = ws + 2639872;
  float* sum4 = ws + 3690496;
  float* tln  = ws + 4739072;
  float* XQ   = ws + 5787648;
  float* XK   = ws + 6836224;
  float* XV   = ws + 7884800;
  float* tout = ws + 8933376;
  float* tfull = sum4;
  float* h2    = bufA;
  float* f1    = XQ;
  float* f2    = tout;

  const int M = 4096;
  dim3 blk(256);

  zero_halo<<<16, blk, 0, stream>>>(bufA, bufB);
  prep_w<<<6208, blk, 0, stream>>>(conv1_w, convs_w, wt1, wt);

  gemm_k<1, 1, 0, 1, 0><<<dim3(64, 4), blk, 0, stream>>>(
      x, wt1, conv1_b, nullptr, bufA, nullptr, M, 256, 64, 64, 0);

  for (int i = 0; i < 8; ++i) {
    const float* in = (i % 2 == 0) ? bufA : bufB;
    float* out = (i % 2 == 0) ? bufB : bufA;
    const float* wp = wt + (size_t)i * 196608;
    const float* bp = convs_b + i * 256;
    if (i == 1)
      gemm_k<1, 1, 0, 1, 1><<<dim3(64, 4), blk, 0, stream>>>(
          in, wp, bp, nullptr, out, sum4, M, 256, 768, 256, 1);
    else if (i == 3 || i == 5 || i == 7)
      gemm_k<1, 1, 0, 1, 2><<<dim3(64, 4), blk, 0, stream>>>(
          in, wp, bp, nullptr, out, sum4, M, 256, 768, 256, 1);
    else
      gemm_k<1, 1, 0, 1, 0><<<dim3(64, 4), blk, 0, stream>>>(
          in, wp, bp, nullptr, out, sum4, M, 256, 768, 256, 1);
  }

  ln_kernel<<<1024, blk, 0, stream>>>(sum4, tln, ln_w, ln_b, 1e-5f);

  gemm_k<0, 0, 0, 2, 0><<<dim3(64, 4), blk, 0, stream>>>(
      tln, wq, nullptr, nullptr, XQ, nullptr, M, 256, 256, 256, 0);
  gemm_k<0, 0, 0, 2, 0><<<dim3(64, 4), blk, 0, stream>>>(
      tln, wk, nullptr, nullptr, XK, nullptr, M, 256, 256, 256, 0);
  gemm_k<0, 0, 0, 2, 0><<<dim3(64, 4), blk, 0, stream>>>(
      tln, wv, nullptr, nullptr, XV, nullptr, M, 256, 256, 256, 0);

  // TTT scan (MFMA): 16 chains, 512 threads, 162688 B dynamic LDS
  const int TTT_LDS = 162688;
  (void)hipFuncSetAttribute((const void*)ttt_mfma,
                            hipFuncAttributeMaxDynamicSharedMemorySize, TTT_LDS);
  ttt_mfma<<<16, dim3(512), TTT_LDS, stream>>>(XQ, XK, XV, ttt_W1, ttt_b1,
                                               ttt_W2, ttt_b2, ttt_lnw, ttt_lnb,
                                               tout);

  gemm_k<0, 0, 1, 0, 0><<<dim3(64, 4), blk, 0, stream>>>(
      tout, wo, nullptr, tln, tfull, nullptr, M, 256, 256, 256, 0);

  ln_kernel<<<1024, blk, 0, stream>>>(tfull, h2, ln_w, ln_b, 1e-5f);

  gemm_k<1, 0, 0, 0, 0><<<dim3(64, 8), blk, 0, stream>>>(
      h2, fc_w, fc_b, nullptr, f1, nullptr, M, 512, 256, 256, 0);
  gemm_k<1, 0, 0, 0, 0><<<dim3(64, 1), blk, 0, stream>>>(
      f1, fc2_w, fc2_b, nullptr, f2, nullptr, M, 64, 512, 512, 0);
  fc3_kernel<<<1024, blk, 0, stream>>>(f2, fc3_w, fc3_b, (float*)d_out);
}